// Round 13
// baseline (339.450 us; speedup 1.0000x reference)
//
#include <hip/hip_runtime.h>
#include <hip/hip_bf16.h>

#define N_ENT   50000
#define N_EDGE  600000
#define FEAT    128
#define HID     256
#define OUT_D   128
#define MROWS   50048        // N_ENT padded to 64
#define BN_EPS  1e-5f
#define SCAN_BLKS 196        // ceil(N_ENT/256)
#define NT      (MROWS / 64) // 782 row-tiles of 64
#define RED_BLKS 196         // ceil(NT/4)

// ---------------- ws layout (bytes) ----------------
#define OFF_DEGI    0               // [N_ENT] i32          200,000
#define OFF_SCALE   202048          // [HID] f32            1,024
#define OFF_SHIFT   203072          // [HID] f32            1,024
#define OFF_RELB    204096          // [101][128] bf16      25,856
#define OFF_WT1     229952          // [256][256] bf16 (WmWsf^T stacked)  131,072
#define OFF_W1T     361024          // [256][256] bf16      131,072
#define OFF_W2T     492096          // [128][256] bf16      65,536
#define OFF_A       557632          // [MROWS][256] bf16 (right half = x bf16)  25,624,576
#define OFF_Y       26182208        // [MROWS][256] bf16 (swizzled granules) 25,624,576
#define OFF_PB      52000000        // [NT][512] f32 partial (cs,cq interleaved) 1,601,536
#define OFF_PB2     53601536        // [196][512] f32 stage-2 partials 401,408
// CSR gets its OWN region (r11/r12 crash: overlaying Y raced with fused k_hy's y-writes)
#define OFF_ROWPTR  55000000        // [N_ENT+1] i32 200,064
#define OFF_FILLC   55200064        // [N_ENT] i32   200,000
#define OFF_PACKED  55400064        // [N_EDGE] i32  2,400,000
#define OFF_BSUM    57800064        // [196] i32
#define OFF_BOFF    57801088        // [196] i32

typedef __attribute__((ext_vector_type(8))) short bf16x8;
typedef __attribute__((ext_vector_type(4))) float f32x4;

#define GLL(gp, lp) __builtin_amdgcn_global_load_lds( \
    (const __attribute__((address_space(1))) void*)(gp), \
    (__attribute__((address_space(3))) void*)(lp), 16, 0, 0)

#define MFMA(a, b, c) __builtin_amdgcn_mfma_f32_16x16x32_bf16((a), (b), (c), 0, 0, 0)

__device__ __forceinline__ ushort f2bf(float f) {
    uint u = __float_as_uint(f);
    return (ushort)((u + 0x7FFFu + ((u >> 16) & 1u)) >> 16);
}
__device__ __forceinline__ float bflo(uint u) { return __uint_as_float(u << 16); }
__device__ __forceinline__ float bfhi(uint u) { return __uint_as_float(u & 0xFFFF0000u); }

// ---- prep (fused): cvt x->A right half | deg histogram | weight transpose+cvt
__global__ __launch_bounds__(256) void k_prep(
    const float* __restrict__ x, const int* __restrict__ ei,
    const float* __restrict__ Wm, const float* __restrict__ Wsf,
    const float* __restrict__ W1, const float* __restrict__ W2,
    const float* __restrict__ rel,
    ushort* __restrict__ A, int* __restrict__ degi,
    ushort* __restrict__ Wt1, ushort* __restrict__ W1t,
    ushort* __restrict__ W2t, ushort* __restrict__ relb)
{
    int b = blockIdx.x;
    if (b < 3125) {
        int idx = b * 256 + threadIdx.x;          // 800,000 exactly
        int m = idx >> 4;
        int c = (idx & 15) * 8;
        float4 f0 = *(const float4*)(x + m * FEAT + c);
        float4 f1 = *(const float4*)(x + m * FEAT + c + 4);
        uint4 o;
        o.x = (uint)f2bf(f0.x) | ((uint)f2bf(f0.y) << 16);
        o.y = (uint)f2bf(f0.z) | ((uint)f2bf(f0.w) << 16);
        o.z = (uint)f2bf(f1.x) | ((uint)f2bf(f1.y) << 16);
        o.w = (uint)f2bf(f1.z) | ((uint)f2bf(f1.w) << 16);
        *(uint4*)(A + m * 256 + FEAT + c) = o;
    } else if (b < 3125 + 2344) {
        int e = (b - 3125) * 256 + threadIdx.x;
        if (e < N_EDGE) atomicAdd(&degi[ei[N_EDGE + e]], 1);
    } else {
        int idx = (b - 5469) * 256 + threadIdx.x;
        if (idx < 65536) {
            int n = idx >> 8, k = idx & 255;
            float v = (k < FEAT) ? Wm[k * HID + n] : Wsf[(k - FEAT) * HID + n];
            Wt1[idx] = f2bf(v);
        } else if (idx < 131072) {
            int o = idx - 65536;
            int n = o >> 8, k = o & 255;
            W1t[o] = f2bf(W1[k * HID + n]);
        } else if (idx < 163840) {
            int o = idx - 131072;
            int n = o >> 8, k = o & 255;
            W2t[o] = f2bf(W2[k * OUT_D + n]);
        } else if (idx < 163840 + 101 * 128) {
            int o = idx - 163840;
            relb[o] = f2bf(rel[o]);
        }
    }
}

// ---- scan pipeline
__global__ __launch_bounds__(256) void k_bsum(
    const int* __restrict__ degi, int* __restrict__ bsum)
{
    __shared__ int red[4];
    int idx = blockIdx.x * 256 + threadIdx.x;
    int v = (idx < N_ENT) ? degi[idx] : 0;
    #pragma unroll
    for (int off = 1; off < 64; off <<= 1) v += __shfl_xor(v, off);
    if ((threadIdx.x & 63) == 0) red[threadIdx.x >> 6] = v;
    __syncthreads();
    if (threadIdx.x == 0) bsum[blockIdx.x] = red[0] + red[1] + red[2] + red[3];
}

__global__ __launch_bounds__(256) void k_boff(
    const int* __restrict__ bsum, int* __restrict__ boff, int* __restrict__ rowptr)
{
    __shared__ int s[256];
    int t = threadIdx.x;
    int v = (t < SCAN_BLKS) ? bsum[t] : 0;
    s[t] = v;
    __syncthreads();
    for (int off = 1; off < 256; off <<= 1) {
        int u = (t >= off) ? s[t - off] : 0;
        __syncthreads();
        s[t] += u;
        __syncthreads();
    }
    if (t < SCAN_BLKS) boff[t] = s[t] - v;
    if (t == 255) rowptr[N_ENT] = s[255];
}

__global__ __launch_bounds__(256) void k_scan2(
    const int* __restrict__ degi, const int* __restrict__ boff,
    int* __restrict__ rowptr, int* __restrict__ fillc)
{
    __shared__ int s[256];
    int t = threadIdx.x;
    int idx = blockIdx.x * 256 + t;
    int v = (idx < N_ENT) ? degi[idx] : 0;
    s[t] = v;
    __syncthreads();
    for (int off = 1; off < 256; off <<= 1) {
        int u = (t >= off) ? s[t - off] : 0;
        __syncthreads();
        s[t] += u;
        __syncthreads();
    }
    if (idx < N_ENT) {
        int ex = s[t] - v + boff[blockIdx.x];
        rowptr[idx] = ex;
        fillc[idx]  = ex;
    }
}

__global__ __launch_bounds__(256) void k_fill(
    const int* __restrict__ ei, const int* __restrict__ et,
    int* __restrict__ fillc, int* __restrict__ packed)
{
    int e = blockIdx.x * 256 + threadIdx.x;
    if (e >= N_EDGE) return;
    int dst = ei[N_EDGE + e];
    int pos = atomicAdd(&fillc[dst], 1);
    packed[pos] = ei[e] | (et[e] << 16);
}

// ---- hy (agg fused): x right-half reg-staged -> swizzled LDS (per-lane ds_write);
// agg 64 nodes -> LDS left half; h = A@Wt1^T + bm ; y = h@W1t^T + b1 ; partials -> pb.
__global__ __launch_bounds__(256) void k_hy(
    const ushort* __restrict__ A, const int* __restrict__ rowptr,
    const int* __restrict__ packed, const ushort* __restrict__ relb,
    const ushort* __restrict__ Wt1, const ushort* __restrict__ W1t,
    const float* __restrict__ bm, const float* __restrict__ b1,
    ushort* __restrict__ y, float* __restrict__ pb)
{
    __shared__ ushort a_s[64 * 256];      // 32 KB; swizzled 16B granules
    int tid = threadIdx.x;
    int w = tid >> 6, l = tid & 63;
    int lr = l & 15, lk = l >> 4;
    int m0 = blockIdx.x * 64;

    // issue x right-half loads EARLY (coalesced 256B runs; latency hides under agg)
    uint4 xstg[4];
    {
        const ushort* srcb = A + (size_t)m0 * 256;
        #pragma unroll
        for (int j = 0; j < 4; ++j) {
            int idx = j * 256 + tid;           // 1024 granules (64 rows x 16)
            int row = idx >> 4, s = idx & 15;
            xstg[j] = *(const uint4*)(srcb + row * 256 + FEAT + s * 8);
        }
    }

    // ---- agg: wave w aggregates nodes m0+w*16 .. +16 -> LDS left half (swizzled)
    for (int i = 0; i < 16; ++i) {
        int r = w * 16 + i;
        int node = m0 + r;
        float ax = 0.f, ay = 0.f;
        float invd = 0.f;
        if (node < N_ENT) {
            int e0 = rowptr[node], e1 = rowptr[node + 1];
            int e = e0;
            for (; e + 8 <= e1; e += 8) {
                int p0 = packed[e],     p1 = packed[e + 1], p2 = packed[e + 2], p3 = packed[e + 3];
                int p4 = packed[e + 4], p5 = packed[e + 5], p6 = packed[e + 6], p7 = packed[e + 7];
                uint xv0 = *(const uint*)(A + (p0 & 0xFFFF) * 256 + FEAT + l * 2);
                uint rv0 = *(const uint*)(relb + (p0 >> 16) * FEAT + l * 2);
                uint xv1 = *(const uint*)(A + (p1 & 0xFFFF) * 256 + FEAT + l * 2);
                uint rv1 = *(const uint*)(relb + (p1 >> 16) * FEAT + l * 2);
                uint xv2 = *(const uint*)(A + (p2 & 0xFFFF) * 256 + FEAT + l * 2);
                uint rv2 = *(const uint*)(relb + (p2 >> 16) * FEAT + l * 2);
                uint xv3 = *(const uint*)(A + (p3 & 0xFFFF) * 256 + FEAT + l * 2);
                uint rv3 = *(const uint*)(relb + (p3 >> 16) * FEAT + l * 2);
                uint xv4 = *(const uint*)(A + (p4 & 0xFFFF) * 256 + FEAT + l * 2);
                uint rv4 = *(const uint*)(relb + (p4 >> 16) * FEAT + l * 2);
                uint xv5 = *(const uint*)(A + (p5 & 0xFFFF) * 256 + FEAT + l * 2);
                uint rv5 = *(const uint*)(relb + (p5 >> 16) * FEAT + l * 2);
                uint xv6 = *(const uint*)(A + (p6 & 0xFFFF) * 256 + FEAT + l * 2);
                uint rv6 = *(const uint*)(relb + (p6 >> 16) * FEAT + l * 2);
                uint xv7 = *(const uint*)(A + (p7 & 0xFFFF) * 256 + FEAT + l * 2);
                uint rv7 = *(const uint*)(relb + (p7 >> 16) * FEAT + l * 2);
                ax += bflo(xv0) + bflo(rv0) + bflo(xv1) + bflo(rv1)
                    + bflo(xv2) + bflo(rv2) + bflo(xv3) + bflo(rv3)
                    + bflo(xv4) + bflo(rv4) + bflo(xv5) + bflo(rv5)
                    + bflo(xv6) + bflo(rv6) + bflo(xv7) + bflo(rv7);
                ay += bfhi(xv0) + bfhi(rv0) + bfhi(xv1) + bfhi(rv1)
                    + bfhi(xv2) + bfhi(rv2) + bfhi(xv3) + bfhi(rv3)
                    + bfhi(xv4) + bfhi(rv4) + bfhi(xv5) + bfhi(rv5)
                    + bfhi(xv6) + bfhi(rv6) + bfhi(xv7) + bfhi(rv7);
            }
            for (; e < e1; ++e) {
                int p = packed[e];
                uint xv = *(const uint*)(A + (p & 0xFFFF) * 256 + FEAT + l * 2);
                uint rv = *(const uint*)(relb + (p >> 16) * FEAT + l * 2);
                ax += bflo(xv) + bflo(rv);
                ay += bfhi(xv) + bfhi(rv);
            }
            invd = 1.0f / fmaxf((float)(e1 - e0), 1.0f);
        }
        uint o = (uint)f2bf(ax * invd) | ((uint)f2bf(ay * invd) << 16);
        // lane l covers cols 2l,2l+1: granule g = l>>2, swizzled g^(r&7)
        int g = l >> 2;
        *(uint*)&a_s[r * 256 + ((g ^ (r & 7)) << 3) + ((l & 3) << 1)] = o;
    }

    // write staged x into swizzled LDS right half (granules 16..31; XOR only bits 0-2)
    #pragma unroll
    for (int j = 0; j < 4; ++j) {
        int idx = j * 256 + tid;
        int row = idx >> 4, s = idx & 15;
        *(uint4*)&a_s[row * 256 + (((16 + s) ^ (row & 7)) << 3)] = xstg[j];
    }
    __syncthreads();

    // ---- phase 1: h = [agg|x] @ [Wm;Wsf] (+bm)
    f32x4 acc[4][4] = {};
    const ushort* Bp = Wt1 + (w * 64 + lr) * 256 + lk * 8;
    for (int k0 = 0; k0 < 256; k0 += 32) {
        bf16x8 a[4], b[4];
        #pragma unroll
        for (int mb = 0; mb < 4; ++mb) {
            int row = mb * 16 + lr;
            a[mb] = *(const bf16x8*)&a_s[row * 256 + ((((k0 >> 3) + lk) ^ (lr & 7)) << 3)];
        }
        #pragma unroll
        for (int nb = 0; nb < 4; ++nb) b[nb] = *(const bf16x8*)(Bp + nb * 4096 + k0);
        #pragma unroll
        for (int mb = 0; mb < 4; ++mb)
            #pragma unroll
            for (int nb = 0; nb < 4; ++nb)
                acc[mb][nb] = MFMA(a[mb], b[nb], acc[mb][nb]);
    }
    __syncthreads();   // a_s reads done; reuse for h

    #pragma unroll
    for (int nb = 0; nb < 4; ++nb) {
        int col = w * 64 + nb * 16 + lr;
        float bias = bm[col];
        #pragma unroll
        for (int mb = 0; mb < 4; ++mb)
            #pragma unroll
            for (int r = 0; r < 4; ++r) {
                int row = mb * 16 + lk * 4 + r;
                a_s[row * 256 + (col ^ ((row & 7) << 3))] = f2bf(acc[mb][nb][r] + bias);
            }
    }
    __syncthreads();

    // ---- phase 2: y = h @ W1 (+b1)
    f32x4 acc2[4][4] = {};
    const ushort* B2p = W1t + (w * 64 + lr) * 256 + lk * 8;
    for (int k0 = 0; k0 < 256; k0 += 32) {
        bf16x8 a[4], b[4];
        #pragma unroll
        for (int mb = 0; mb < 4; ++mb) {
            int row = mb * 16 + lr;
            a[mb] = *(const bf16x8*)&a_s[row * 256 + ((k0 + lk * 8) ^ ((row & 7) << 3))];
        }
        #pragma unroll
        for (int nb = 0; nb < 4; ++nb) b[nb] = *(const bf16x8*)(B2p + nb * 4096 + k0);
        #pragma unroll
        for (int mb = 0; mb < 4; ++mb)
            #pragma unroll
            for (int nb = 0; nb < 4; ++nb)
                acc2[mb][nb] = MFMA(a[mb], b[nb], acc2[mb][nb]);
    }
    __syncthreads();   // h reads done; reuse a_s for y staging

    #pragma unroll
    for (int nb = 0; nb < 4; ++nb) {
        int col = w * 64 + nb * 16 + lr;
        float b1v = b1[col];
        float cs = 0.f, cq = 0.f;
        #pragma unroll
        for (int mb = 0; mb < 4; ++mb)
            #pragma unroll
            for (int r = 0; r < 4; ++r) {
                int row = mb * 16 + lk * 4 + r;
                float v = acc2[mb][nb][r] + b1v;
                if (m0 + row < N_ENT) { cs += v; cq += v * v; }
                a_s[row * 256 + (col ^ ((row & 7) << 3))] = f2bf(v);
            }
        cs += __shfl_xor(cs, 16); cs += __shfl_xor(cs, 32);
        cq += __shfl_xor(cq, 16); cq += __shfl_xor(cq, 32);
        if (lk == 0) {
            *(float2*)(pb + (size_t)blockIdx.x * 512 + col * 2) = make_float2(cs, cq);
        }
    }
    __syncthreads();
    ushort* yp = y + (size_t)m0 * 256;
    #pragma unroll
    for (int i = 0; i < 8; ++i) {
        int off = i * 2048 + tid * 8;
        *(uint4*)(yp + off) = *(const uint4*)&a_s[off];
    }
}

// ---- red1: parallel stage-1 reduce: 196 blocks x 4 tiles -> pb2[196][512]
__global__ __launch_bounds__(256) void k_red1(
    const float* __restrict__ pb, float* __restrict__ pb2)
{
    int b = blockIdx.x, tid = threadIdx.x;
    int t0 = b * 4;
    float sx = 0.f, sy = 0.f;
    #pragma unroll
    for (int i = 0; i < 4; ++i) {
        int t = t0 + i;
        if (t < NT) {
            float2 v = *(const float2*)(pb + (size_t)t * 512 + tid * 2);
            sx += v.x; sy += v.y;
        }
    }
    *(float2*)(pb2 + (size_t)b * 512 + tid * 2) = make_float2(sx, sy);
}

// ---- red2: stage-2 reduce + BN finalize
__global__ __launch_bounds__(256) void k_red2(
    const float* __restrict__ pb2,
    const float* __restrict__ gamma, const float* __restrict__ beta,
    float* __restrict__ scale, float* __restrict__ shift)
{
    int c = threadIdx.x;
    float s = 0.f, q = 0.f;
    int b = 0;
    #pragma unroll
    for (; b + 8 <= RED_BLKS; b += 8) {
        float2 v0 = *(const float2*)(pb2 + (size_t)(b + 0) * 512 + c * 2);
        float2 v1 = *(const float2*)(pb2 + (size_t)(b + 1) * 512 + c * 2);
        float2 v2 = *(const float2*)(pb2 + (size_t)(b + 2) * 512 + c * 2);
        float2 v3 = *(const float2*)(pb2 + (size_t)(b + 3) * 512 + c * 2);
        float2 v4 = *(const float2*)(pb2 + (size_t)(b + 4) * 512 + c * 2);
        float2 v5 = *(const float2*)(pb2 + (size_t)(b + 5) * 512 + c * 2);
        float2 v6 = *(const float2*)(pb2 + (size_t)(b + 6) * 512 + c * 2);
        float2 v7 = *(const float2*)(pb2 + (size_t)(b + 7) * 512 + c * 2);
        s += v0.x + v1.x + v2.x + v3.x + v4.x + v5.x + v6.x + v7.x;
        q += v0.y + v1.y + v2.y + v3.y + v4.y + v5.y + v6.y + v7.y;
    }
    for (; b < RED_BLKS; ++b) {
        float2 v = *(const float2*)(pb2 + (size_t)b * 512 + c * 2);
        s += v.x; q += v.y;
    }
    const float invn = 1.0f / (float)N_ENT;
    float mean = s * invn;
    float var  = q * invn - mean * mean;
    float rstd = rsqrtf(var + BN_EPS);
    float sc   = gamma[c] * rstd;
    scale[c] = sc;
    shift[c] = beta[c] - mean * sc;
}

// ---- zout: out = relu(y*scale+shift) @ W2t^T + b2.
__global__ __launch_bounds__(256) void k_zout(
    const ushort* __restrict__ y, const float* __restrict__ scale,
    const float* __restrict__ shift, const ushort* __restrict__ W2t,
    const float* __restrict__ b2, float* __restrict__ out)
{
    __shared__ ushort z_s[64 * 256];
    int tid = threadIdx.x;
    int w = tid >> 6, l = tid & 63;
    int lr = l & 15, lk = l >> 4;
    int m0 = blockIdx.x * 64;

    {
        const ushort* srcb = y + (size_t)m0 * 256;
        #pragma unroll
        for (int j = 0; j < 8; ++j)
            GLL(srcb + ((w * 8 + j) * 64 + l) * 8, &z_s[(w * 8 + j) * 512]);
    }
    __syncthreads();

    f32x4 acc[4][2] = {};
    const ushort* Bp = W2t + (w * 32 + lr) * 256 + lk * 8;
    for (int k0 = 0; k0 < 256; k0 += 32) {
        int kb = k0 + lk * 8;
        float scv[8], shv[8];
        *(float4*)&scv[0] = *(const float4*)(scale + kb);
        *(float4*)&scv[4] = *(const float4*)(scale + kb + 4);
        *(float4*)&shv[0] = *(const float4*)(shift + kb);
        *(float4*)&shv[4] = *(const float4*)(shift + kb + 4);
        bf16x8 b[2];
        #pragma unroll
        for (int nb = 0; nb < 2; ++nb) b[nb] = *(const bf16x8*)(Bp + nb * 4096 + k0);
        bf16x8 a[4];
        #pragma unroll
        for (int mb = 0; mb < 4; ++mb) {
            int row = mb * 16 + lr;
            uint4 uv = *(const uint4*)&z_s[row * 256 + (kb ^ ((row & 7) << 3))];
            uint wd[4] = {uv.x, uv.y, uv.z, uv.w};
            #pragma unroll
            for (int j = 0; j < 8; ++j) {
                uint bits = (j & 1) ? (wd[j >> 1] & 0xFFFF0000u) : (wd[j >> 1] << 16);
                float f = __uint_as_float(bits);
                float z = fmaxf(f * scv[j] + shv[j], 0.f);
                a[mb][j] = (short)f2bf(z);
            }
        }
        #pragma unroll
        for (int mb = 0; mb < 4; ++mb)
            #pragma unroll
            for (int nb = 0; nb < 2; ++nb)
                acc[mb][nb] = MFMA(a[mb], b[nb], acc[mb][nb]);
    }
    #pragma unroll
    for (int nb = 0; nb < 2; ++nb) {
        int col = w * 32 + nb * 16 + lr;
        float b2v = b2[col];
        #pragma unroll
        for (int mb = 0; mb < 4; ++mb)
            #pragma unroll
            for (int r = 0; r < 4; ++r) {
                int row = m0 + mb * 16 + lk * 4 + r;
                if (row < N_ENT) out[row * OUT_D + col] = acc[mb][nb][r] + b2v;
            }
    }
}

extern "C" void kernel_launch(void* const* d_in, const int* in_sizes, int n_in,
                              void* d_out, int out_size, void* d_ws, size_t ws_size,
                              hipStream_t stream)
{
    const int*   ei    = (const int*)d_in[0];
    const int*   et    = (const int*)d_in[1];
    const float* x     = (const float*)d_in[2];
    const float* rel   = (const float*)d_in[3];
    const float* Wm    = (const float*)d_in[4];
    const float* bm    = (const float*)d_in[5];
    const float* Wsf   = (const float*)d_in[6];
    const float* W1    = (const float*)d_in[7];
    const float* b1    = (const float*)d_in[8];
    const float* gamma = (const float*)d_in[9];
    const float* beta  = (const float*)d_in[10];
    const float* W2    = (const float*)d_in[11];
    const float* b2    = (const float*)d_in[12];
    float* out = (float*)d_out;

    char* ws = (char*)d_ws;
    int*    degi   = (int*)(ws + OFF_DEGI);
    float*  scale  = (float*)(ws + OFF_SCALE);
    float*  shift  = (float*)(ws + OFF_SHIFT);
    ushort* relb   = (ushort*)(ws + OFF_RELB);
    ushort* Wt1    = (ushort*)(ws + OFF_WT1);
    ushort* W1t    = (ushort*)(ws + OFF_W1T);
    ushort* W2t    = (ushort*)(ws + OFF_W2T);
    ushort* A      = (ushort*)(ws + OFF_A);
    ushort* y      = (ushort*)(ws + OFF_Y);
    int*    rowptr = (int*)(ws + OFF_ROWPTR);
    int*    fillc  = (int*)(ws + OFF_FILLC);
    int*    packed = (int*)(ws + OFF_PACKED);
    int*    bsum   = (int*)(ws + OFF_BSUM);
    int*    boff   = (int*)(ws + OFF_BOFF);
    float*  pb     = (float*)(ws + OFF_PB);
    float*  pb2    = (float*)(ws + OFF_PB2);

    hipMemsetAsync(ws + OFF_DEGI, 0, 202048, stream);
    hipMemsetAsync(ws + OFF_A + N_ENT * 512, 0, (MROWS - N_ENT) * 512, stream);

    k_prep <<<6160, 256, 0, stream>>>(x, ei, Wm, Wsf, W1, W2, rel, A, degi, Wt1, W1t, W2t, relb);
    k_bsum <<<SCAN_BLKS, 256, 0, stream>>>(degi, bsum);
    k_boff <<<1, 256, 0, stream>>>(bsum, boff, rowptr);
    k_scan2<<<SCAN_BLKS, 256, 0, stream>>>(degi, boff, rowptr, fillc);
    k_fill <<<(N_EDGE + 255) / 256, 256, 0, stream>>>(ei, et, fillc, packed);
    k_hy   <<<NT, 256, 0, stream>>>(A, rowptr, packed, relb, Wt1, W1t, bm, b1, y, pb);
    k_red1 <<<RED_BLKS, 256, 0, stream>>>(pb, pb2);
    k_red2 <<<1, 256, 0, stream>>>(pb2, gamma, beta, scale, shift);
    k_zout <<<NT, 256, 0, stream>>>(y, scale, shift, W2t, b2, out);
}

// Round 14
// 194.361 us; speedup vs baseline: 1.7465x; 1.7465x over previous
//
#include <hip/hip_runtime.h>
#include <hip/hip_bf16.h>

#define N_ENT   50000
#define N_EDGE  600000
#define FEAT    128
#define HID     256
#define OUT_D   128
#define MROWS   50048        // N_ENT padded to 64
#define BN_EPS  1e-5f
#define SCAN_BLKS 196        // ceil(N_ENT/256)
#define NT      (MROWS / 64) // 782 row-tiles of 64
#define RED_BLKS 196         // ceil(NT/4)

// ---------------- ws layout (bytes) ----------------
#define OFF_DEGI    0               // [N_ENT] i32          200,000
#define OFF_SCALE   202048          // [HID] f32            1,024
#define OFF_SHIFT   203072          // [HID] f32            1,024
#define OFF_RELB    204096          // [101][128] bf16      25,856
#define OFF_WT1     229952          // [256][256] bf16 (WmWsf^T stacked)  131,072
#define OFF_W1T     361024          // [256][256] bf16      131,072
#define OFF_W2T     492096          // [128][256] bf16      65,536
#define OFF_A       557632          // [MROWS][256] bf16 ([agg|x], linear)  25,624,576
#define OFF_Y       26182208        // [MROWS][256] bf16 (swizzled granules) 25,624,576
#define OFF_PB      52000000        // [NT][512] f32 partial (cs,cq interleaved) 1,601,536
#define OFF_PB2     53601536        // [196][512] f32 stage-2 partials 401,408
// CSR in its own region (r12 lesson: never overlay buffers whose lifetimes overlap)
#define OFF_ROWPTR  55000000        // [N_ENT+1] i32 200,064
#define OFF_FILLC   55200064        // [N_ENT] i32   200,000
#define OFF_PACKED  55400064        // [N_EDGE] i32  2,400,000
#define OFF_BSUM    57800064        // [196] i32
#define OFF_BOFF    57801088        // [196] i32

typedef __attribute__((ext_vector_type(8))) short bf16x8;
typedef __attribute__((ext_vector_type(4))) float f32x4;

#define GLL(gp, lp) __builtin_amdgcn_global_load_lds( \
    (const __attribute__((address_space(1))) void*)(gp), \
    (__attribute__((address_space(3))) void*)(lp), 16, 0, 0)

#define MFMA(a, b, c) __builtin_amdgcn_mfma_f32_16x16x32_bf16((a), (b), (c), 0, 0, 0)

__device__ __forceinline__ ushort f2bf(float f) {
    uint u = __float_as_uint(f);
    return (ushort)((u + 0x7FFFu + ((u >> 16) & 1u)) >> 16);
}
__device__ __forceinline__ float bflo(uint u) { return __uint_as_float(u << 16); }
__device__ __forceinline__ float bfhi(uint u) { return __uint_as_float(u & 0xFFFF0000u); }

// ---- prep (fused): cvt x->A right half | deg histogram | weight transpose+cvt
__global__ __launch_bounds__(256) void k_prep(
    const float* __restrict__ x, const int* __restrict__ ei,
    const float* __restrict__ Wm, const float* __restrict__ Wsf,
    const float* __restrict__ W1, const float* __restrict__ W2,
    const float* __restrict__ rel,
    ushort* __restrict__ A, int* __restrict__ degi,
    ushort* __restrict__ Wt1, ushort* __restrict__ W1t,
    ushort* __restrict__ W2t, ushort* __restrict__ relb)
{
    int b = blockIdx.x;
    if (b < 3125) {
        int idx = b * 256 + threadIdx.x;          // 800,000 exactly
        int m = idx >> 4;
        int c = (idx & 15) * 8;
        float4 f0 = *(const float4*)(x + m * FEAT + c);
        float4 f1 = *(const float4*)(x + m * FEAT + c + 4);
        uint4 o;
        o.x = (uint)f2bf(f0.x) | ((uint)f2bf(f0.y) << 16);
        o.y = (uint)f2bf(f0.z) | ((uint)f2bf(f0.w) << 16);
        o.z = (uint)f2bf(f1.x) | ((uint)f2bf(f1.y) << 16);
        o.w = (uint)f2bf(f1.z) | ((uint)f2bf(f1.w) << 16);
        *(uint4*)(A + m * 256 + FEAT + c) = o;
    } else if (b < 3125 + 2344) {
        int e = (b - 3125) * 256 + threadIdx.x;
        if (e < N_EDGE) atomicAdd(&degi[ei[N_EDGE + e]], 1);
    } else {
        int idx = (b - 5469) * 256 + threadIdx.x;
        if (idx < 65536) {
            int n = idx >> 8, k = idx & 255;
            float v = (k < FEAT) ? Wm[k * HID + n] : Wsf[(k - FEAT) * HID + n];
            Wt1[idx] = f2bf(v);
        } else if (idx < 131072) {
            int o = idx - 65536;
            int n = o >> 8, k = o & 255;
            W1t[o] = f2bf(W1[k * HID + n]);
        } else if (idx < 163840) {
            int o = idx - 131072;
            int n = o >> 8, k = o & 255;
            W2t[o] = f2bf(W2[k * OUT_D + n]);
        } else if (idx < 163840 + 101 * 128) {
            int o = idx - 163840;
            relb[o] = f2bf(rel[o]);
        }
    }
}

// ---- scan pipeline
__global__ __launch_bounds__(256) void k_bsum(
    const int* __restrict__ degi, int* __restrict__ bsum)
{
    __shared__ int red[4];
    int idx = blockIdx.x * 256 + threadIdx.x;
    int v = (idx < N_ENT) ? degi[idx] : 0;
    #pragma unroll
    for (int off = 1; off < 64; off <<= 1) v += __shfl_xor(v, off);
    if ((threadIdx.x & 63) == 0) red[threadIdx.x >> 6] = v;
    __syncthreads();
    if (threadIdx.x == 0) bsum[blockIdx.x] = red[0] + red[1] + red[2] + red[3];
}

__global__ __launch_bounds__(256) void k_boff(
    const int* __restrict__ bsum, int* __restrict__ boff, int* __restrict__ rowptr)
{
    __shared__ int s[256];
    int t = threadIdx.x;
    int v = (t < SCAN_BLKS) ? bsum[t] : 0;
    s[t] = v;
    __syncthreads();
    for (int off = 1; off < 256; off <<= 1) {
        int u = (t >= off) ? s[t - off] : 0;
        __syncthreads();
        s[t] += u;
        __syncthreads();
    }
    if (t < SCAN_BLKS) boff[t] = s[t] - v;
    if (t == 255) rowptr[N_ENT] = s[255];
}

__global__ __launch_bounds__(256) void k_scan2(
    const int* __restrict__ degi, const int* __restrict__ boff,
    int* __restrict__ rowptr, int* __restrict__ fillc)
{
    __shared__ int s[256];
    int t = threadIdx.x;
    int idx = blockIdx.x * 256 + t;
    int v = (idx < N_ENT) ? degi[idx] : 0;
    s[t] = v;
    __syncthreads();
    for (int off = 1; off < 256; off <<= 1) {
        int u = (t >= off) ? s[t - off] : 0;
        __syncthreads();
        s[t] += u;
        __syncthreads();
    }
    if (idx < N_ENT) {
        int ex = s[t] - v + boff[blockIdx.x];
        rowptr[idx] = ex;
        fillc[idx]  = ex;
    }
}

__global__ __launch_bounds__(256) void k_fill(
    const int* __restrict__ ei, const int* __restrict__ et,
    int* __restrict__ fillc, int* __restrict__ packed)
{
    int e = blockIdx.x * 256 + threadIdx.x;
    if (e >= N_EDGE) return;
    int dst = ei[N_EDGE + e];
    int pos = atomicAdd(&fillc[dst], 1);
    packed[pos] = ei[e] | (et[e] << 16);
}

// ---- agg: segment mean over bf16 gathers -> left half of A (linear).
// One node per wave: gather parallelism is the whole game here (r13 lesson).
__global__ __launch_bounds__(256) void k_agg(
    const int* __restrict__ rowptr, const int* __restrict__ packed,
    ushort* __restrict__ A, const ushort* __restrict__ relb)
{
    int node = blockIdx.x * 4 + (threadIdx.x >> 6);
    int lane = threadIdx.x & 63;
    int e0 = rowptr[node], e1 = rowptr[node + 1];
    float ax = 0.f, ay = 0.f;
    int e = e0;
    for (; e + 8 <= e1; e += 8) {
        int p0 = packed[e],     p1 = packed[e + 1], p2 = packed[e + 2], p3 = packed[e + 3];
        int p4 = packed[e + 4], p5 = packed[e + 5], p6 = packed[e + 6], p7 = packed[e + 7];
        uint xv0 = *(const uint*)(A + (p0 & 0xFFFF) * 256 + FEAT + lane * 2);
        uint rv0 = *(const uint*)(relb + (p0 >> 16) * FEAT + lane * 2);
        uint xv1 = *(const uint*)(A + (p1 & 0xFFFF) * 256 + FEAT + lane * 2);
        uint rv1 = *(const uint*)(relb + (p1 >> 16) * FEAT + lane * 2);
        uint xv2 = *(const uint*)(A + (p2 & 0xFFFF) * 256 + FEAT + lane * 2);
        uint rv2 = *(const uint*)(relb + (p2 >> 16) * FEAT + lane * 2);
        uint xv3 = *(const uint*)(A + (p3 & 0xFFFF) * 256 + FEAT + lane * 2);
        uint rv3 = *(const uint*)(relb + (p3 >> 16) * FEAT + lane * 2);
        uint xv4 = *(const uint*)(A + (p4 & 0xFFFF) * 256 + FEAT + lane * 2);
        uint rv4 = *(const uint*)(relb + (p4 >> 16) * FEAT + lane * 2);
        uint xv5 = *(const uint*)(A + (p5 & 0xFFFF) * 256 + FEAT + lane * 2);
        uint rv5 = *(const uint*)(relb + (p5 >> 16) * FEAT + lane * 2);
        uint xv6 = *(const uint*)(A + (p6 & 0xFFFF) * 256 + FEAT + lane * 2);
        uint rv6 = *(const uint*)(relb + (p6 >> 16) * FEAT + lane * 2);
        uint xv7 = *(const uint*)(A + (p7 & 0xFFFF) * 256 + FEAT + lane * 2);
        uint rv7 = *(const uint*)(relb + (p7 >> 16) * FEAT + lane * 2);
        ax += bflo(xv0) + bflo(rv0) + bflo(xv1) + bflo(rv1)
            + bflo(xv2) + bflo(rv2) + bflo(xv3) + bflo(rv3)
            + bflo(xv4) + bflo(rv4) + bflo(xv5) + bflo(rv5)
            + bflo(xv6) + bflo(rv6) + bflo(xv7) + bflo(rv7);
        ay += bfhi(xv0) + bfhi(rv0) + bfhi(xv1) + bfhi(rv1)
            + bfhi(xv2) + bfhi(rv2) + bfhi(xv3) + bfhi(rv3)
            + bfhi(xv4) + bfhi(rv4) + bfhi(xv5) + bfhi(rv5)
            + bfhi(xv6) + bfhi(rv6) + bfhi(xv7) + bfhi(rv7);
    }
    for (; e < e1; ++e) {
        int p = packed[e];
        uint xv = *(const uint*)(A + (p & 0xFFFF) * 256 + FEAT + lane * 2);
        uint rv = *(const uint*)(relb + (p >> 16) * FEAT + lane * 2);
        ax += bflo(xv) + bflo(rv);
        ay += bfhi(xv) + bfhi(rv);
    }
    float invd = 1.0f / fmaxf((float)(e1 - e0), 1.0f);
    uint o = (uint)f2bf(ax * invd) | ((uint)f2bf(ay * invd) << 16);
    *(uint*)(A + node * 256 + lane * 2) = o;
}

// ---- hy: fused h = A@Wt1^T + bm ; y = h@W1t^T + b1 ; NO atomics (partials -> pb).
__global__ __launch_bounds__(256) void k_hy(
    const ushort* __restrict__ A, const ushort* __restrict__ Wt1,
    const ushort* __restrict__ W1t,
    const float* __restrict__ bm, const float* __restrict__ b1,
    ushort* __restrict__ y, float* __restrict__ pb)
{
    __shared__ ushort a_s[64 * 256];      // 32 KB; swizzled 16B granules
    int tid = threadIdx.x;
    int w = tid >> 6, l = tid & 63;
    int lr = l & 15, lk = l >> 4;
    int m0 = blockIdx.x * 64;

    // stage A-tile: LDS linear, global source swizzled
    {
        const ushort* srcb = A + (size_t)m0 * 256;
        #pragma unroll
        for (int j = 0; j < 8; ++j) {
            int slot = (w * 8 + j) * 64 + l;
            int lrow = slot >> 5, lgr = slot & 31;
            GLL(srcb + lrow * 256 + ((lgr ^ (lrow & 7)) << 3), &a_s[(w * 8 + j) * 512]);
        }
    }
    __syncthreads();

    // ---- phase 1: h = [agg|x] @ [Wm;Wsf] (+bm)
    f32x4 acc[4][4] = {};
    const ushort* Bp = Wt1 + (w * 64 + lr) * 256 + lk * 8;
    for (int k0 = 0; k0 < 256; k0 += 32) {
        bf16x8 a[4], b[4];
        #pragma unroll
        for (int mb = 0; mb < 4; ++mb) {
            int row = mb * 16 + lr;
            a[mb] = *(const bf16x8*)&a_s[row * 256 + ((((k0 >> 3) + lk) ^ (lr & 7)) << 3)];
        }
        #pragma unroll
        for (int nb = 0; nb < 4; ++nb) b[nb] = *(const bf16x8*)(Bp + nb * 4096 + k0);
        #pragma unroll
        for (int mb = 0; mb < 4; ++mb)
            #pragma unroll
            for (int nb = 0; nb < 4; ++nb)
                acc[mb][nb] = MFMA(a[mb], b[nb], acc[mb][nb]);
    }
    __syncthreads();   // a_s reads done; reuse for h

    #pragma unroll
    for (int nb = 0; nb < 4; ++nb) {
        int col = w * 64 + nb * 16 + lr;
        float bias = bm[col];
        #pragma unroll
        for (int mb = 0; mb < 4; ++mb)
            #pragma unroll
            for (int r = 0; r < 4; ++r) {
                int row = mb * 16 + lk * 4 + r;
                a_s[row * 256 + (col ^ ((row & 7) << 3))] = f2bf(acc[mb][nb][r] + bias);
            }
    }
    __syncthreads();

    // ---- phase 2: y = h @ W1 (+b1)
    f32x4 acc2[4][4] = {};
    const ushort* B2p = W1t + (w * 64 + lr) * 256 + lk * 8;
    for (int k0 = 0; k0 < 256; k0 += 32) {
        bf16x8 a[4], b[4];
        #pragma unroll
        for (int mb = 0; mb < 4; ++mb) {
            int row = mb * 16 + lr;
            a[mb] = *(const bf16x8*)&a_s[row * 256 + ((k0 + lk * 8) ^ ((row & 7) << 3))];
        }
        #pragma unroll
        for (int nb = 0; nb < 4; ++nb) b[nb] = *(const bf16x8*)(B2p + nb * 4096 + k0);
        #pragma unroll
        for (int mb = 0; mb < 4; ++mb)
            #pragma unroll
            for (int nb = 0; nb < 4; ++nb)
                acc2[mb][nb] = MFMA(a[mb], b[nb], acc2[mb][nb]);
    }
    __syncthreads();   // h reads done; reuse a_s for y staging

    #pragma unroll
    for (int nb = 0; nb < 4; ++nb) {
        int col = w * 64 + nb * 16 + lr;
        float b1v = b1[col];
        float cs = 0.f, cq = 0.f;
        #pragma unroll
        for (int mb = 0; mb < 4; ++mb)
            #pragma unroll
            for (int r = 0; r < 4; ++r) {
                int row = mb * 16 + lk * 4 + r;
                float v = acc2[mb][nb][r] + b1v;
                if (m0 + row < N_ENT) { cs += v; cq += v * v; }
                a_s[row * 256 + (col ^ ((row & 7) << 3))] = f2bf(v);
            }
        cs += __shfl_xor(cs, 16); cs += __shfl_xor(cs, 32);
        cq += __shfl_xor(cq, 16); cq += __shfl_xor(cq, 32);
        if (lk == 0) {
            *(float2*)(pb + (size_t)blockIdx.x * 512 + col * 2) = make_float2(cs, cq);
        }
    }
    __syncthreads();
    ushort* yp = y + (size_t)m0 * 256;
    #pragma unroll
    for (int i = 0; i < 8; ++i) {
        int off = i * 2048 + tid * 8;
        *(uint4*)(yp + off) = *(const uint4*)&a_s[off];
    }
}

// ---- red1: parallel stage-1 reduce: 196 blocks x 4 tiles -> pb2[196][512]
__global__ __launch_bounds__(256) void k_red1(
    const float* __restrict__ pb, float* __restrict__ pb2)
{
    int b = blockIdx.x, tid = threadIdx.x;
    int t0 = b * 4;
    float sx = 0.f, sy = 0.f;
    #pragma unroll
    for (int i = 0; i < 4; ++i) {
        int t = t0 + i;
        if (t < NT) {
            float2 v = *(const float2*)(pb + (size_t)t * 512 + tid * 2);
            sx += v.x; sy += v.y;
        }
    }
    *(float2*)(pb2 + (size_t)b * 512 + tid * 2) = make_float2(sx, sy);
}

// ---- red2: stage-2 reduce + BN finalize
__global__ __launch_bounds__(256) void k_red2(
    const float* __restrict__ pb2,
    const float* __restrict__ gamma, const float* __restrict__ beta,
    float* __restrict__ scale, float* __restrict__ shift)
{
    int c = threadIdx.x;
    float s = 0.f, q = 0.f;
    int b = 0;
    #pragma unroll
    for (; b + 8 <= RED_BLKS; b += 8) {
        float2 v0 = *(const float2*)(pb2 + (size_t)(b + 0) * 512 + c * 2);
        float2 v1 = *(const float2*)(pb2 + (size_t)(b + 1) * 512 + c * 2);
        float2 v2 = *(const float2*)(pb2 + (size_t)(b + 2) * 512 + c * 2);
        float2 v3 = *(const float2*)(pb2 + (size_t)(b + 3) * 512 + c * 2);
        float2 v4 = *(const float2*)(pb2 + (size_t)(b + 4) * 512 + c * 2);
        float2 v5 = *(const float2*)(pb2 + (size_t)(b + 5) * 512 + c * 2);
        float2 v6 = *(const float2*)(pb2 + (size_t)(b + 6) * 512 + c * 2);
        float2 v7 = *(const float2*)(pb2 + (size_t)(b + 7) * 512 + c * 2);
        s += v0.x + v1.x + v2.x + v3.x + v4.x + v5.x + v6.x + v7.x;
        q += v0.y + v1.y + v2.y + v3.y + v4.y + v5.y + v6.y + v7.y;
    }
    for (; b < RED_BLKS; ++b) {
        float2 v = *(const float2*)(pb2 + (size_t)b * 512 + c * 2);
        s += v.x; q += v.y;
    }
    const float invn = 1.0f / (float)N_ENT;
    float mean = s * invn;
    float var  = q * invn - mean * mean;
    float rstd = rsqrtf(var + BN_EPS);
    float sc   = gamma[c] * rstd;
    scale[c] = sc;
    shift[c] = beta[c] - mean * sc;
}

// ---- zout: out = relu(y*scale+shift) @ W2t^T + b2.
__global__ __launch_bounds__(256) void k_zout(
    const ushort* __restrict__ y, const float* __restrict__ scale,
    const float* __restrict__ shift, const ushort* __restrict__ W2t,
    const float* __restrict__ b2, float* __restrict__ out)
{
    __shared__ ushort z_s[64 * 256];
    int tid = threadIdx.x;
    int w = tid >> 6, l = tid & 63;
    int lr = l & 15, lk = l >> 4;
    int m0 = blockIdx.x * 64;

    {
        const ushort* srcb = y + (size_t)m0 * 256;
        #pragma unroll
        for (int j = 0; j < 8; ++j)
            GLL(srcb + ((w * 8 + j) * 64 + l) * 8, &z_s[(w * 8 + j) * 512]);
    }
    __syncthreads();

    f32x4 acc[4][2] = {};
    const ushort* Bp = W2t + (w * 32 + lr) * 256 + lk * 8;
    for (int k0 = 0; k0 < 256; k0 += 32) {
        int kb = k0 + lk * 8;
        float scv[8], shv[8];
        *(float4*)&scv[0] = *(const float4*)(scale + kb);
        *(float4*)&scv[4] = *(const float4*)(scale + kb + 4);
        *(float4*)&shv[0] = *(const float4*)(shift + kb);
        *(float4*)&shv[4] = *(const float4*)(shift + kb + 4);
        bf16x8 b[2];
        #pragma unroll
        for (int nb = 0; nb < 2; ++nb) b[nb] = *(const bf16x8*)(Bp + nb * 4096 + k0);
        bf16x8 a[4];
        #pragma unroll
        for (int mb = 0; mb < 4; ++mb) {
            int row = mb * 16 + lr;
            uint4 uv = *(const uint4*)&z_s[row * 256 + (kb ^ ((row & 7) << 3))];
            uint wd[4] = {uv.x, uv.y, uv.z, uv.w};
            #pragma unroll
            for (int j = 0; j < 8; ++j) {
                uint bits = (j & 1) ? (wd[j >> 1] & 0xFFFF0000u) : (wd[j >> 1] << 16);
                float f = __uint_as_float(bits);
                float z = fmaxf(f * scv[j] + shv[j], 0.f);
                a[mb][j] = (short)f2bf(z);
            }
        }
        #pragma unroll
        for (int mb = 0; mb < 4; ++mb)
            #pragma unroll
            for (int nb = 0; nb < 2; ++nb)
                acc[mb][nb] = MFMA(a[mb], b[nb], acc[mb][nb]);
    }
    #pragma unroll
    for (int nb = 0; nb < 2; ++nb) {
        int col = w * 32 + nb * 16 + lr;
        float b2v = b2[col];
        #pragma unroll
        for (int mb = 0; mb < 4; ++mb)
            #pragma unroll
            for (int r = 0; r < 4; ++r) {
                int row = m0 + mb * 16 + lk * 4 + r;
                if (row < N_ENT) out[row * OUT_D + col] = acc[mb][nb][r] + b2v;
            }
    }
}

extern "C" void kernel_launch(void* const* d_in, const int* in_sizes, int n_in,
                              void* d_out, int out_size, void* d_ws, size_t ws_size,
                              hipStream_t stream)
{
    const int*   ei    = (const int*)d_in[0];
    const int*   et    = (const int*)d_in[1];
    const float* x     = (const float*)d_in[2];
    const float* rel   = (const float*)d_in[3];
    const float* Wm    = (const float*)d_in[4];
    const float* bm    = (const float*)d_in[5];
    const float* Wsf   = (const float*)d_in[6];
    const float* W1    = (const float*)d_in[7];
    const float* b1    = (const float*)d_in[8];
    const float* gamma = (const float*)d_in[9];
    const float* beta  = (const float*)d_in[10];
    const float* W2    = (const float*)d_in[11];
    const float* b2    = (const float*)d_in[12];
    float* out = (float*)d_out;

    char* ws = (char*)d_ws;
    int*    degi   = (int*)(ws + OFF_DEGI);
    float*  scale  = (float*)(ws + OFF_SCALE);
    float*  shift  = (float*)(ws + OFF_SHIFT);
    ushort* relb   = (ushort*)(ws + OFF_RELB);
    ushort* Wt1    = (ushort*)(ws + OFF_WT1);
    ushort* W1t    = (ushort*)(ws + OFF_W1T);
    ushort* W2t    = (ushort*)(ws + OFF_W2T);
    ushort* A      = (ushort*)(ws + OFF_A);
    ushort* y      = (ushort*)(ws + OFF_Y);
    int*    rowptr = (int*)(ws + OFF_ROWPTR);
    int*    fillc  = (int*)(ws + OFF_FILLC);
    int*    packed = (int*)(ws + OFF_PACKED);
    int*    bsum   = (int*)(ws + OFF_BSUM);
    int*    boff   = (int*)(ws + OFF_BOFF);
    float*  pb     = (float*)(ws + OFF_PB);
    float*  pb2    = (float*)(ws + OFF_PB2);

    hipMemsetAsync(ws + OFF_DEGI, 0, 202048, stream);
    hipMemsetAsync(ws + OFF_A + N_ENT * 512, 0, (MROWS - N_ENT) * 512, stream);

    k_prep <<<6160, 256, 0, stream>>>(x, ei, Wm, Wsf, W1, W2, rel, A, degi, Wt1, W1t, W2t, relb);
    k_bsum <<<SCAN_BLKS, 256, 0, stream>>>(degi, bsum);
    k_boff <<<1, 256, 0, stream>>>(bsum, boff, rowptr);
    k_scan2<<<SCAN_BLKS, 256, 0, stream>>>(degi, boff, rowptr, fillc);
    k_fill <<<(N_EDGE + 255) / 256, 256, 0, stream>>>(ei, et, fillc, packed);
    k_agg  <<<N_ENT / 4, 256, 0, stream>>>(rowptr, packed, A, relb);
    k_hy   <<<NT, 256, 0, stream>>>(A, Wt1, W1t, bm, b1, y, pb);
    k_red1 <<<RED_BLKS, 256, 0, stream>>>(pb, pb2);
    k_red2 <<<1, 256, 0, stream>>>(pb2, gamma, beta, scale, shift);
    k_zout <<<NT, 256, 0, stream>>>(y, scale, shift, W2t, b2, out);
}

// Round 16
// 188.348 us; speedup vs baseline: 1.8022x; 1.0319x over previous
//
#include <hip/hip_runtime.h>
#include <hip/hip_bf16.h>

#define N_ENT   50000
#define N_EDGE  600000
#define FEAT    128
#define HID     256
#define OUT_D   128
#define MROWS   50048        // N_ENT padded to 64
#define BN_EPS  1e-5f
#define SCAN_BLKS 196        // ceil(N_ENT/256)
#define NT      (MROWS / 64) // 782 row-tiles of 64
#define RED_BLKS 196         // ceil(NT/4)

// ---------------- ws layout (bytes) ----------------
#define OFF_DEGI    0               // [N_ENT] i32          200,000
#define OFF_SCALE   202048          // [HID] f32            1,024
#define OFF_SHIFT   203072          // [HID] f32            1,024
#define OFF_RELB    204096          // [101][128] bf16      25,856
#define OFF_WT1     229952          // [256][256] bf16 (WmWsf^T stacked)  131,072
#define OFF_W1T     361024          // [256][256] bf16      131,072
#define OFF_W2T     492096          // [128][256] bf16      65,536
#define OFF_A       557632          // [MROWS][256] bf16 ([agg|x], linear)  25,624,576
#define OFF_Y       26182208        // [MROWS][256] bf16 (swizzled granules) 25,624,576
#define OFF_PB      52000000        // [NT][512] f32 partial (cs,cq interleaved) 1,601,536
#define OFF_PB2     53601536        // [196][512] f32 stage-2 partials 401,408
// CSR in its own region (r12 lesson: never overlay buffers whose lifetimes overlap)
#define OFF_ROWPTR  55000000        // [N_ENT+1] i32 200,064
#define OFF_FILLC   55200064        // [N_ENT] i32   200,000
#define OFF_PACKED  55400064        // [N_EDGE] i32  2,400,000
#define OFF_BSUM    57800064        // [196] i32
#define OFF_BOFF    57801088        // [196] i32

typedef __attribute__((ext_vector_type(8))) short bf16x8;
typedef __attribute__((ext_vector_type(4))) float f32x4;

#define GLL(gp, lp) __builtin_amdgcn_global_load_lds( \
    (const __attribute__((address_space(1))) void*)(gp), \
    (__attribute__((address_space(3))) void*)(lp), 16, 0, 0)

#define MFMA(a, b, c) __builtin_amdgcn_mfma_f32_16x16x32_bf16((a), (b), (c), 0, 0, 0)

__device__ __forceinline__ ushort f2bf(float f) {
    uint u = __float_as_uint(f);
    return (ushort)((u + 0x7FFFu + ((u >> 16) & 1u)) >> 16);
}
__device__ __forceinline__ float bflo(uint u) { return __uint_as_float(u << 16); }
__device__ __forceinline__ float bfhi(uint u) { return __uint_as_float(u & 0xFFFF0000u); }

// ---- prep (fused): cvt x->A right half | deg histogram | weight transpose+cvt
__global__ __launch_bounds__(256) void k_prep(
    const float* __restrict__ x, const int* __restrict__ ei,
    const float* __restrict__ Wm, const float* __restrict__ Wsf,
    const float* __restrict__ W1, const float* __restrict__ W2,
    const float* __restrict__ rel,
    ushort* __restrict__ A, int* __restrict__ degi,
    ushort* __restrict__ Wt1, ushort* __restrict__ W1t,
    ushort* __restrict__ W2t, ushort* __restrict__ relb)
{
    int b = blockIdx.x;
    if (b < 3125) {
        int idx = b * 256 + threadIdx.x;          // 800,000 exactly
        int m = idx >> 4;
        int c = (idx & 15) * 8;
        float4 f0 = *(const float4*)(x + m * FEAT + c);
        float4 f1 = *(const float4*)(x + m * FEAT + c + 4);
        uint4 o;
        o.x = (uint)f2bf(f0.x) | ((uint)f2bf(f0.y) << 16);
        o.y = (uint)f2bf(f0.z) | ((uint)f2bf(f0.w) << 16);
        o.z = (uint)f2bf(f1.x) | ((uint)f2bf(f1.y) << 16);
        o.w = (uint)f2bf(f1.z) | ((uint)f2bf(f1.w) << 16);
        *(uint4*)(A + m * 256 + FEAT + c) = o;
    } else if (b < 3125 + 2344) {
        int e = (b - 3125) * 256 + threadIdx.x;
        if (e < N_EDGE) atomicAdd(&degi[ei[N_EDGE + e]], 1);
    } else {
        int idx = (b - 5469) * 256 + threadIdx.x;
        if (idx < 65536) {
            int n = idx >> 8, k = idx & 255;
            float v = (k < FEAT) ? Wm[k * HID + n] : Wsf[(k - FEAT) * HID + n];
            Wt1[idx] = f2bf(v);
        } else if (idx < 131072) {
            int o = idx - 65536;
            int n = o >> 8, k = o & 255;
            W1t[o] = f2bf(W1[k * HID + n]);
        } else if (idx < 163840) {
            int o = idx - 131072;
            int n = o >> 8, k = o & 255;
            W2t[o] = f2bf(W2[k * OUT_D + n]);
        } else if (idx < 163840 + 101 * 128) {
            int o = idx - 163840;
            relb[o] = f2bf(rel[o]);
        }
    }
}

// ---- scan pipeline
__global__ __launch_bounds__(256) void k_bsum(
    const int* __restrict__ degi, int* __restrict__ bsum)
{
    __shared__ int red[4];
    int idx = blockIdx.x * 256 + threadIdx.x;
    int v = (idx < N_ENT) ? degi[idx] : 0;
    #pragma unroll
    for (int off = 1; off < 64; off <<= 1) v += __shfl_xor(v, off);
    if ((threadIdx.x & 63) == 0) red[threadIdx.x >> 6] = v;
    __syncthreads();
    if (threadIdx.x == 0) bsum[blockIdx.x] = red[0] + red[1] + red[2] + red[3];
}

__global__ __launch_bounds__(256) void k_boff(
    const int* __restrict__ bsum, int* __restrict__ boff, int* __restrict__ rowptr)
{
    __shared__ int s[256];
    int t = threadIdx.x;
    int v = (t < SCAN_BLKS) ? bsum[t] : 0;
    s[t] = v;
    __syncthreads();
    for (int off = 1; off < 256; off <<= 1) {
        int u = (t >= off) ? s[t - off] : 0;
        __syncthreads();
        s[t] += u;
        __syncthreads();
    }
    if (t < SCAN_BLKS) boff[t] = s[t] - v;
    if (t == 255) rowptr[N_ENT] = s[255];
}

__global__ __launch_bounds__(256) void k_scan2(
    const int* __restrict__ degi, const int* __restrict__ boff,
    int* __restrict__ rowptr, int* __restrict__ fillc)
{
    __shared__ int s[256];
    int t = threadIdx.x;
    int idx = blockIdx.x * 256 + t;
    int v = (idx < N_ENT) ? degi[idx] : 0;
    s[t] = v;
    __syncthreads();
    for (int off = 1; off < 256; off <<= 1) {
        int u = (t >= off) ? s[t - off] : 0;
        __syncthreads();
        s[t] += u;
        __syncthreads();
    }
    if (idx < N_ENT) {
        int ex = s[t] - v + boff[blockIdx.x];
        rowptr[idx] = ex;
        fillc[idx]  = ex;
    }
}

__global__ __launch_bounds__(256) void k_fill(
    const int* __restrict__ ei, const int* __restrict__ et,
    int* __restrict__ fillc, int* __restrict__ packed)
{
    int e = blockIdx.x * 256 + threadIdx.x;
    if (e >= N_EDGE) return;
    int dst = ei[N_EDGE + e];
    int pos = atomicAdd(&fillc[dst], 1);
    packed[pos] = ei[e] | (et[e] << 16);
}

// ---- agg: segment mean, one node/wave; 8/4/2/1 MLP ladder (serial tail cut 7->3 rounds)
__global__ __launch_bounds__(256) void k_agg(
    const int* __restrict__ rowptr, const int* __restrict__ packed,
    ushort* __restrict__ A, const ushort* __restrict__ relb)
{
    int node = blockIdx.x * 4 + (threadIdx.x >> 6);
    int lane = threadIdx.x & 63;
    int e0 = rowptr[node], e1 = rowptr[node + 1];
    float ax = 0.f, ay = 0.f;
    int e = e0;
    for (; e + 8 <= e1; e += 8) {
        int p0 = packed[e],     p1 = packed[e + 1], p2 = packed[e + 2], p3 = packed[e + 3];
        int p4 = packed[e + 4], p5 = packed[e + 5], p6 = packed[e + 6], p7 = packed[e + 7];
        uint xv0 = *(const uint*)(A + (p0 & 0xFFFF) * 256 + FEAT + lane * 2);
        uint rv0 = *(const uint*)(relb + (p0 >> 16) * FEAT + lane * 2);
        uint xv1 = *(const uint*)(A + (p1 & 0xFFFF) * 256 + FEAT + lane * 2);
        uint rv1 = *(const uint*)(relb + (p1 >> 16) * FEAT + lane * 2);
        uint xv2 = *(const uint*)(A + (p2 & 0xFFFF) * 256 + FEAT + lane * 2);
        uint rv2 = *(const uint*)(relb + (p2 >> 16) * FEAT + lane * 2);
        uint xv3 = *(const uint*)(A + (p3 & 0xFFFF) * 256 + FEAT + lane * 2);
        uint rv3 = *(const uint*)(relb + (p3 >> 16) * FEAT + lane * 2);
        uint xv4 = *(const uint*)(A + (p4 & 0xFFFF) * 256 + FEAT + lane * 2);
        uint rv4 = *(const uint*)(relb + (p4 >> 16) * FEAT + lane * 2);
        uint xv5 = *(const uint*)(A + (p5 & 0xFFFF) * 256 + FEAT + lane * 2);
        uint rv5 = *(const uint*)(relb + (p5 >> 16) * FEAT + lane * 2);
        uint xv6 = *(const uint*)(A + (p6 & 0xFFFF) * 256 + FEAT + lane * 2);
        uint rv6 = *(const uint*)(relb + (p6 >> 16) * FEAT + lane * 2);
        uint xv7 = *(const uint*)(A + (p7 & 0xFFFF) * 256 + FEAT + lane * 2);
        uint rv7 = *(const uint*)(relb + (p7 >> 16) * FEAT + lane * 2);
        ax += bflo(xv0) + bflo(rv0) + bflo(xv1) + bflo(rv1)
            + bflo(xv2) + bflo(rv2) + bflo(xv3) + bflo(rv3)
            + bflo(xv4) + bflo(rv4) + bflo(xv5) + bflo(rv5)
            + bflo(xv6) + bflo(rv6) + bflo(xv7) + bflo(rv7);
        ay += bfhi(xv0) + bfhi(rv0) + bfhi(xv1) + bfhi(rv1)
            + bfhi(xv2) + bfhi(rv2) + bfhi(xv3) + bfhi(rv3)
            + bfhi(xv4) + bfhi(rv4) + bfhi(xv5) + bfhi(rv5)
            + bfhi(xv6) + bfhi(rv6) + bfhi(xv7) + bfhi(rv7);
    }
    for (; e + 4 <= e1; e += 4) {
        int p0 = packed[e], p1 = packed[e + 1], p2 = packed[e + 2], p3 = packed[e + 3];
        uint xv0 = *(const uint*)(A + (p0 & 0xFFFF) * 256 + FEAT + lane * 2);
        uint rv0 = *(const uint*)(relb + (p0 >> 16) * FEAT + lane * 2);
        uint xv1 = *(const uint*)(A + (p1 & 0xFFFF) * 256 + FEAT + lane * 2);
        uint rv1 = *(const uint*)(relb + (p1 >> 16) * FEAT + lane * 2);
        uint xv2 = *(const uint*)(A + (p2 & 0xFFFF) * 256 + FEAT + lane * 2);
        uint rv2 = *(const uint*)(relb + (p2 >> 16) * FEAT + lane * 2);
        uint xv3 = *(const uint*)(A + (p3 & 0xFFFF) * 256 + FEAT + lane * 2);
        uint rv3 = *(const uint*)(relb + (p3 >> 16) * FEAT + lane * 2);
        ax += bflo(xv0) + bflo(rv0) + bflo(xv1) + bflo(rv1)
            + bflo(xv2) + bflo(rv2) + bflo(xv3) + bflo(rv3);
        ay += bfhi(xv0) + bfhi(rv0) + bfhi(xv1) + bfhi(rv1)
            + bfhi(xv2) + bfhi(rv2) + bfhi(xv3) + bfhi(rv3);
    }
    for (; e + 2 <= e1; e += 2) {
        int p0 = packed[e], p1 = packed[e + 1];
        uint xv0 = *(const uint*)(A + (p0 & 0xFFFF) * 256 + FEAT + lane * 2);
        uint rv0 = *(const uint*)(relb + (p0 >> 16) * FEAT + lane * 2);
        uint xv1 = *(const uint*)(A + (p1 & 0xFFFF) * 256 + FEAT + lane * 2);
        uint rv1 = *(const uint*)(relb + (p1 >> 16) * FEAT + lane * 2);
        ax += bflo(xv0) + bflo(rv0) + bflo(xv1) + bflo(rv1);
        ay += bfhi(xv0) + bfhi(rv0) + bfhi(xv1) + bfhi(rv1);
    }
    if (e < e1) {
        int p = packed[e];
        uint xv = *(const uint*)(A + (p & 0xFFFF) * 256 + FEAT + lane * 2);
        uint rv = *(const uint*)(relb + (p >> 16) * FEAT + lane * 2);
        ax += bflo(xv) + bflo(rv);
        ay += bfhi(xv) + bfhi(rv);
    }
    float invd = 1.0f / fmaxf((float)(e1 - e0), 1.0f);
    uint o = (uint)f2bf(ax * invd) | ((uint)f2bf(ay * invd) << 16);
    *(uint*)(A + node * 256 + lane * 2) = o;
}

// ---- hy: fused h = A@Wt1^T + bm ; y = h@W1t^T + b1 ; NO atomics (partials -> pb).
__global__ __launch_bounds__(256) void k_hy(
    const ushort* __restrict__ A, const ushort* __restrict__ Wt1,
    const ushort* __restrict__ W1t,
    const float* __restrict__ bm, const float* __restrict__ b1,
    ushort* __restrict__ y, float* __restrict__ pb)
{
    __shared__ ushort a_s[64 * 256];      // 32 KB; swizzled 16B granules
    int tid = threadIdx.x;
    int w = tid >> 6, l = tid & 63;
    int lr = l & 15, lk = l >> 4;
    int m0 = blockIdx.x * 64;

    // stage A-tile: LDS linear, global source swizzled
    {
        const ushort* srcb = A + (size_t)m0 * 256;
        #pragma unroll
        for (int j = 0; j < 8; ++j) {
            int slot = (w * 8 + j) * 64 + l;
            int lrow = slot >> 5, lgr = slot & 31;
            GLL(srcb + lrow * 256 + ((lgr ^ (lrow & 7)) << 3), &a_s[(w * 8 + j) * 512]);
        }
    }
    __syncthreads();

    // ---- phase 1: h = [agg|x] @ [Wm;Wsf] (+bm)
    f32x4 acc[4][4] = {};
    const ushort* Bp = Wt1 + (w * 64 + lr) * 256 + lk * 8;
    for (int k0 = 0; k0 < 256; k0 += 32) {
        bf16x8 a[4], b[4];
        #pragma unroll
        for (int mb = 0; mb < 4; ++mb) {
            int row = mb * 16 + lr;
            a[mb] = *(const bf16x8*)&a_s[row * 256 + ((((k0 >> 3) + lk) ^ (lr & 7)) << 3)];
        }
        #pragma unroll
        for (int nb = 0; nb < 4; ++nb) b[nb] = *(const bf16x8*)(Bp + nb * 4096 + k0);
        #pragma unroll
        for (int mb = 0; mb < 4; ++mb)
            #pragma unroll
            for (int nb = 0; nb < 4; ++nb)
                acc[mb][nb] = MFMA(a[mb], b[nb], acc[mb][nb]);
    }
    __syncthreads();   // a_s reads done; reuse for h

    #pragma unroll
    for (int nb = 0; nb < 4; ++nb) {
        int col = w * 64 + nb * 16 + lr;
        float bias = bm[col];
        #pragma unroll
        for (int mb = 0; mb < 4; ++mb)
            #pragma unroll
            for (int r = 0; r < 4; ++r) {
                int row = mb * 16 + lk * 4 + r;
                a_s[row * 256 + (col ^ ((row & 7) << 3))] = f2bf(acc[mb][nb][r] + bias);
            }
    }
    __syncthreads();

    // ---- phase 2: y = h @ W1 (+b1)
    f32x4 acc2[4][4] = {};
    const ushort* B2p = W1t + (w * 64 + lr) * 256 + lk * 8;
    for (int k0 = 0; k0 < 256; k0 += 32) {
        bf16x8 a[4], b[4];
        #pragma unroll
        for (int mb = 0; mb < 4; ++mb) {
            int row = mb * 16 + lr;
            a[mb] = *(const bf16x8*)&a_s[row * 256 + ((k0 + lk * 8) ^ ((row & 7) << 3))];
        }
        #pragma unroll
        for (int nb = 0; nb < 4; ++nb) b[nb] = *(const bf16x8*)(B2p + nb * 4096 + k0);
        #pragma unroll
        for (int mb = 0; mb < 4; ++mb)
            #pragma unroll
            for (int nb = 0; nb < 4; ++nb)
                acc2[mb][nb] = MFMA(a[mb], b[nb], acc2[mb][nb]);
    }
    __syncthreads();   // h reads done; reuse a_s for y staging

    #pragma unroll
    for (int nb = 0; nb < 4; ++nb) {
        int col = w * 64 + nb * 16 + lr;
        float b1v = b1[col];
        float cs = 0.f, cq = 0.f;
        #pragma unroll
        for (int mb = 0; mb < 4; ++mb)
            #pragma unroll
            for (int r = 0; r < 4; ++r) {
                int row = mb * 16 + lk * 4 + r;
                float v = acc2[mb][nb][r] + b1v;
                if (m0 + row < N_ENT) { cs += v; cq += v * v; }
                a_s[row * 256 + (col ^ ((row & 7) << 3))] = f2bf(v);
            }
        cs += __shfl_xor(cs, 16); cs += __shfl_xor(cs, 32);
        cq += __shfl_xor(cq, 16); cq += __shfl_xor(cq, 32);
        if (lk == 0) {
            *(float2*)(pb + (size_t)blockIdx.x * 512 + col * 2) = make_float2(cs, cq);
        }
    }
    __syncthreads();
    ushort* yp = y + (size_t)m0 * 256;
    #pragma unroll
    for (int i = 0; i < 8; ++i) {
        int off = i * 2048 + tid * 8;
        *(uint4*)(yp + off) = *(const uint4*)&a_s[off];
    }
}

// ---- red1: parallel stage-1 reduce: 196 blocks x 4 tiles -> pb2[196][512]
__global__ __launch_bounds__(256) void k_red1(
    const float* __restrict__ pb, float* __restrict__ pb2)
{
    int b = blockIdx.x, tid = threadIdx.x;
    int t0 = b * 4;
    float sx = 0.f, sy = 0.f;
    #pragma unroll
    for (int i = 0; i < 4; ++i) {
        int t = t0 + i;
        if (t < NT) {
            float2 v = *(const float2*)(pb + (size_t)t * 512 + tid * 2);
            sx += v.x; sy += v.y;
        }
    }
    *(float2*)(pb2 + (size_t)b * 512 + tid * 2) = make_float2(sx, sy);
}

// ---- red2: stage-2 reduce + BN finalize
__global__ __launch_bounds__(256) void k_red2(
    const float* __restrict__ pb2,
    const float* __restrict__ gamma, const float* __restrict__ beta,
    float* __restrict__ scale, float* __restrict__ shift)
{
    int c = threadIdx.x;
    float s = 0.f, q = 0.f;
    int b = 0;
    #pragma unroll
    for (; b + 8 <= RED_BLKS; b += 8) {
        float2 v0 = *(const float2*)(pb2 + (size_t)(b + 0) * 512 + c * 2);
        float2 v1 = *(const float2*)(pb2 + (size_t)(b + 1) * 512 + c * 2);
        float2 v2 = *(const float2*)(pb2 + (size_t)(b + 2) * 512 + c * 2);
        float2 v3 = *(const float2*)(pb2 + (size_t)(b + 3) * 512 + c * 2);
        float2 v4 = *(const float2*)(pb2 + (size_t)(b + 4) * 512 + c * 2);
        float2 v5 = *(const float2*)(pb2 + (size_t)(b + 5) * 512 + c * 2);
        float2 v6 = *(const float2*)(pb2 + (size_t)(b + 6) * 512 + c * 2);
        float2 v7 = *(const float2*)(pb2 + (size_t)(b + 7) * 512 + c * 2);
        s += v0.x + v1.x + v2.x + v3.x + v4.x + v5.x + v6.x + v7.x;
        q += v0.y + v1.y + v2.y + v3.y + v4.y + v5.y + v6.y + v7.y;
    }
    for (; b < RED_BLKS; ++b) {
        float2 v = *(const float2*)(pb2 + (size_t)b * 512 + c * 2);
        s += v.x; q += v.y;
    }
    const float invn = 1.0f / (float)N_ENT;
    float mean = s * invn;
    float var  = q * invn - mean * mean;
    float rstd = rsqrtf(var + BN_EPS);
    float sc   = gamma[c] * rstd;
    scale[c] = sc;
    shift[c] = beta[c] - mean * sc;
}

// ---- zout: out = relu(y*scale+shift) @ W2t^T + b2.
__global__ __launch_bounds__(256) void k_zout(
    const ushort* __restrict__ y, const float* __restrict__ scale,
    const float* __restrict__ shift, const ushort* __restrict__ W2t,
    const float* __restrict__ b2, float* __restrict__ out)
{
    __shared__ ushort z_s[64 * 256];
    int tid = threadIdx.x;
    int w = tid >> 6, l = tid & 63;
    int lr = l & 15, lk = l >> 4;
    int m0 = blockIdx.x * 64;

    {
        const ushort* srcb = y + (size_t)m0 * 256;
        #pragma unroll
        for (int j = 0; j < 8; ++j)
            GLL(srcb + ((w * 8 + j) * 64 + l) * 8, &z_s[(w * 8 + j) * 512]);
    }
    __syncthreads();

    f32x4 acc[4][2] = {};
    const ushort* Bp = W2t + (w * 32 + lr) * 256 + lk * 8;
    for (int k0 = 0; k0 < 256; k0 += 32) {
        int kb = k0 + lk * 8;
        float scv[8], shv[8];
        *(float4*)&scv[0] = *(const float4*)(scale + kb);
        *(float4*)&scv[4] = *(const float4*)(scale + kb + 4);
        *(float4*)&shv[0] = *(const float4*)(shift + kb);
        *(float4*)&shv[4] = *(const float4*)(shift + kb + 4);
        bf16x8 b[2];
        #pragma unroll
        for (int nb = 0; nb < 2; ++nb) b[nb] = *(const bf16x8*)(Bp + nb * 4096 + k0);
        bf16x8 a[4];
        #pragma unroll
        for (int mb = 0; mb < 4; ++mb) {
            int row = mb * 16 + lr;
            uint4 uv = *(const uint4*)&z_s[row * 256 + (kb ^ ((row & 7) << 3))];
            uint wd[4] = {uv.x, uv.y, uv.z, uv.w};
            #pragma unroll
            for (int j = 0; j < 8; ++j) {
                uint bits = (j & 1) ? (wd[j >> 1] & 0xFFFF0000u) : (wd[j >> 1] << 16);
                float f = __uint_as_float(bits);
                float z = fmaxf(f * scv[j] + shv[j], 0.f);
                a[mb][j] = (short)f2bf(z);
            }
        }
        #pragma unroll
        for (int mb = 0; mb < 4; ++mb)
            #pragma unroll
            for (int nb = 0; nb < 2; ++nb)
                acc[mb][nb] = MFMA(a[mb], b[nb], acc[mb][nb]);
    }
    #pragma unroll
    for (int nb = 0; nb < 2; ++nb) {
        int col = w * 32 + nb * 16 + lr;
        float b2v = b2[col];
        #pragma unroll
        for (int mb = 0; mb < 4; ++mb)
            #pragma unroll
            for (int r = 0; r < 4; ++r) {
                int row = m0 + mb * 16 + lk * 4 + r;
                if (row < N_ENT) out[row * OUT_D + col] = acc[mb][nb][r] + b2v;
            }
    }
}

extern "C" void kernel_launch(void* const* d_in, const int* in_sizes, int n_in,
                              void* d_out, int out_size, void* d_ws, size_t ws_size,
                              hipStream_t stream)
{
    const int*   ei    = (const int*)d_in[0];
    const int*   et    = (const int*)d_in[1];
    const float* x     = (const float*)d_in[2];
    const float* rel   = (const float*)d_in[3];
    const float* Wm    = (const float*)d_in[4];
    const float* bm    = (const float*)d_in[5];
    const float* Wsf   = (const float*)d_in[6];
    const float* W1    = (const float*)d_in[7];
    const float* b1    = (const float*)d_in[8];
    const float* gamma = (const float*)d_in[9];
    const float* beta  = (const float*)d_in[10];
    const float* W2    = (const float*)d_in[11];
    const float* b2    = (const float*)d_in[12];
    float* out = (float*)d_out;

    char* ws = (char*)d_ws;
    int*    degi   = (int*)(ws + OFF_DEGI);
    float*  scale  = (float*)(ws + OFF_SCALE);
    float*  shift  = (float*)(ws + OFF_SHIFT);
    ushort* relb   = (ushort*)(ws + OFF_RELB);
    ushort* Wt1    = (ushort*)(ws + OFF_WT1);
    ushort* W1t    = (ushort*)(ws + OFF_W1T);
    ushort* W2t    = (ushort*)(ws + OFF_W2T);
    ushort* A      = (ushort*)(ws + OFF_A);
    ushort* y      = (ushort*)(ws + OFF_Y);
    int*    rowptr = (int*)(ws + OFF_ROWPTR);
    int*    fillc  = (int*)(ws + OFF_FILLC);
    int*    packed = (int*)(ws + OFF_PACKED);
    int*    bsum   = (int*)(ws + OFF_BSUM);
    int*    boff   = (int*)(ws + OFF_BOFF);
    float*  pb     = (float*)(ws + OFF_PB);
    float*  pb2    = (float*)(ws + OFF_PB2);

    hipMemsetAsync(ws + OFF_DEGI, 0, 200000, stream);
    hipMemsetAsync(ws + OFF_A + N_ENT * 512, 0, (MROWS - N_ENT) * 512, stream);

    k_prep <<<6160, 256, 0, stream>>>(x, ei, Wm, Wsf, W1, W2, rel, A, degi, Wt1, W1t, W2t, relb);
    k_bsum <<<SCAN_BLKS, 256, 0, stream>>>(degi, bsum);
    k_boff <<<1, 256, 0, stream>>>(bsum, boff, rowptr);
    k_scan2<<<SCAN_BLKS, 256, 0, stream>>>(degi, boff, rowptr, fillc);
    k_fill <<<(N_EDGE + 255) / 256, 256, 0, stream>>>(ei, et, fillc, packed);
    k_agg  <<<N_ENT / 4, 256, 0, stream>>>(rowptr, packed, A, relb);
    k_hy   <<<NT, 256, 0, stream>>>(A, Wt1, W1t, bm, b1, y, pb);
    k_red1 <<<RED_BLKS, 256, 0, stream>>>(pb, pb2);
    k_red2 <<<1, 256, 0, stream>>>(pb2, gamma, beta, scale, shift);
    k_zout <<<NT, 256, 0, stream>>>(y, scale, shift, W2t, b2, out);
}

// Round 17
// 178.648 us; speedup vs baseline: 1.9001x; 1.0543x over previous
//
#include <hip/hip_runtime.h>
#include <hip/hip_bf16.h>

#define N_ENT   50000
#define N_EDGE  600000
#define FEAT    128
#define HID     256
#define OUT_D   128
#define MROWS   50048        // N_ENT padded to 64
#define BN_EPS  1e-5f
#define SCAN_BLKS 196        // ceil(N_ENT/256)
#define NT      (MROWS / 64) // 782 row-tiles of 64
#define RED_BLKS 196         // ceil(NT/4)

// ---------------- ws layout (bytes) ----------------
#define OFF_DEGI    0               // [N_ENT] i32          200,000
#define OFF_SCALE   202048          // [HID] f32            1,024
#define OFF_SHIFT   203072          // [HID] f32            1,024
#define OFF_RELB    204096          // [101][128] bf16      25,856
#define OFF_WT1     229952          // fragment-major packed WmWsf^T  131,072
#define OFF_W1T     361024          // fragment-major packed W1^T     131,072
#define OFF_W2T     492096          // fragment-major packed W2^T     65,536
#define OFF_A       557632          // [MROWS][256] bf16 ([agg|x], linear)  25,624,576
#define OFF_Y       26182208        // [MROWS][256] bf16 (swizzled granules) 25,624,576
#define OFF_PB      52000000        // [NT][512] f32 partial (cs,cq interleaved) 1,601,536
#define OFF_PB2     53601536        // [196][512] f32 stage-2 partials 401,408
// CSR in its own region (r12 lesson: never overlay buffers whose lifetimes overlap)
#define OFF_ROWPTR  55000000        // [N_ENT+1] i32 200,064
#define OFF_FILLC   55200064        // [N_ENT] i32   200,000
#define OFF_PACKED  55400064        // [N_EDGE] i32  2,400,000
#define OFF_BSUM    57800064        // [196] i32
#define OFF_BOFF    57801088        // [196] i32

typedef __attribute__((ext_vector_type(8))) short bf16x8;
typedef __attribute__((ext_vector_type(4))) float f32x4;

#define GLL(gp, lp) __builtin_amdgcn_global_load_lds( \
    (const __attribute__((address_space(1))) void*)(gp), \
    (__attribute__((address_space(3))) void*)(lp), 16, 0, 0)

#define MFMA(a, b, c) __builtin_amdgcn_mfma_f32_16x16x32_bf16((a), (b), (c), 0, 0, 0)

__device__ __forceinline__ ushort f2bf(float f) {
    uint u = __float_as_uint(f);
    return (ushort)((u + 0x7FFFu + ((u >> 16) & 1u)) >> 16);
}
__device__ __forceinline__ float bflo(uint u) { return __uint_as_float(u << 16); }
__device__ __forceinline__ float bfhi(uint u) { return __uint_as_float(u & 0xFFFF0000u); }

// ---- prep (fused): cvt x->A right half | deg histogram | weight pack (fragment-major)
// B pack: wave w, k-step kk, col-block nb, lane l=lk*16+lr holds row(w,nb,lr) cols kk*32+lk*8..+8
// -> every k_hy/k_zout B-load is one contiguous 1KB wave transaction.
__global__ __launch_bounds__(256) void k_prep(
    const float* __restrict__ x, const int* __restrict__ ei,
    const float* __restrict__ Wm, const float* __restrict__ Wsf,
    const float* __restrict__ W1, const float* __restrict__ W2,
    const float* __restrict__ rel,
    ushort* __restrict__ A, int* __restrict__ degi,
    ushort* __restrict__ Wt1, ushort* __restrict__ W1t,
    ushort* __restrict__ W2t, ushort* __restrict__ relb)
{
    int b = blockIdx.x;
    if (b < 3125) {
        int idx = b * 256 + threadIdx.x;          // 800,000 exactly
        int m = idx >> 4;
        int c = (idx & 15) * 8;
        float4 f0 = *(const float4*)(x + m * FEAT + c);
        float4 f1 = *(const float4*)(x + m * FEAT + c + 4);
        uint4 o;
        o.x = (uint)f2bf(f0.x) | ((uint)f2bf(f0.y) << 16);
        o.y = (uint)f2bf(f0.z) | ((uint)f2bf(f0.w) << 16);
        o.z = (uint)f2bf(f1.x) | ((uint)f2bf(f1.y) << 16);
        o.w = (uint)f2bf(f1.z) | ((uint)f2bf(f1.w) << 16);
        *(uint4*)(A + m * 256 + FEAT + c) = o;
    } else if (b < 3125 + 2344) {
        int e = (b - 3125) * 256 + threadIdx.x;
        if (e < N_EDGE) atomicAdd(&degi[ei[N_EDGE + e]], 1);
    } else {
        int idx = (b - 5469) * 256 + threadIdx.x;
        if (idx < 65536) {                 // Wt1 pack: n=col(0..255), k=contraction
            int n = idx >> 8, k = idx & 255;
            float v = (k < FEAT) ? Wm[k * HID + n] : Wsf[(k - FEAT) * HID + n];
            int w = n >> 6, nb = (n >> 4) & 3, lr = n & 15;
            int kk = k >> 5, lk = (k >> 3) & 3, j = k & 7;
            int l = lk * 16 + lr;
            Wt1[(((w * 8 + kk) * 4 + nb) * 64 + l) * 8 + j] = f2bf(v);
        } else if (idx < 131072) {         // W1t pack
            int o = idx - 65536;
            int n = o >> 8, k = o & 255;
            float v = W1[k * HID + n];
            int w = n >> 6, nb = (n >> 4) & 3, lr = n & 15;
            int kk = k >> 5, lk = (k >> 3) & 3, j = k & 7;
            int l = lk * 16 + lr;
            W1t[(((w * 8 + kk) * 4 + nb) * 64 + l) * 8 + j] = f2bf(v);
        } else if (idx < 163840) {         // W2t pack (n=0..127, nb in {0,1})
            int o = idx - 131072;
            int n = o >> 8, k = o & 255;
            float v = W2[k * OUT_D + n];
            int w = n >> 5, nb = (n >> 4) & 1, lr = n & 15;
            int kk = k >> 5, lk = (k >> 3) & 3, j = k & 7;
            int l = lk * 16 + lr;
            W2t[(((w * 8 + kk) * 2 + nb) * 64 + l) * 8 + j] = f2bf(v);
        } else if (idx < 163840 + 101 * 128) {
            int o = idx - 163840;
            relb[o] = f2bf(rel[o]);
        }
    }
}

// ---- scan pipeline
__global__ __launch_bounds__(256) void k_bsum(
    const int* __restrict__ degi, int* __restrict__ bsum)
{
    __shared__ int red[4];
    int idx = blockIdx.x * 256 + threadIdx.x;
    int v = (idx < N_ENT) ? degi[idx] : 0;
    #pragma unroll
    for (int off = 1; off < 64; off <<= 1) v += __shfl_xor(v, off);
    if ((threadIdx.x & 63) == 0) red[threadIdx.x >> 6] = v;
    __syncthreads();
    if (threadIdx.x == 0) bsum[blockIdx.x] = red[0] + red[1] + red[2] + red[3];
}

__global__ __launch_bounds__(256) void k_boff(
    const int* __restrict__ bsum, int* __restrict__ boff, int* __restrict__ rowptr)
{
    __shared__ int s[256];
    int t = threadIdx.x;
    int v = (t < SCAN_BLKS) ? bsum[t] : 0;
    s[t] = v;
    __syncthreads();
    for (int off = 1; off < 256; off <<= 1) {
        int u = (t >= off) ? s[t - off] : 0;
        __syncthreads();
        s[t] += u;
        __syncthreads();
    }
    if (t < SCAN_BLKS) boff[t] = s[t] - v;
    if (t == 255) rowptr[N_ENT] = s[255];
}

__global__ __launch_bounds__(256) void k_scan2(
    const int* __restrict__ degi, const int* __restrict__ boff,
    int* __restrict__ rowptr, int* __restrict__ fillc)
{
    __shared__ int s[256];
    int t = threadIdx.x;
    int idx = blockIdx.x * 256 + t;
    int v = (idx < N_ENT) ? degi[idx] : 0;
    s[t] = v;
    __syncthreads();
    for (int off = 1; off < 256; off <<= 1) {
        int u = (t >= off) ? s[t - off] : 0;
        __syncthreads();
        s[t] += u;
        __syncthreads();
    }
    if (idx < N_ENT) {
        int ex = s[t] - v + boff[blockIdx.x];
        rowptr[idx] = ex;
        fillc[idx]  = ex;
    }
}

__global__ __launch_bounds__(256) void k_fill(
    const int* __restrict__ ei, const int* __restrict__ et,
    int* __restrict__ fillc, int* __restrict__ packed)
{
    int e = blockIdx.x * 256 + threadIdx.x;
    if (e >= N_EDGE) return;
    int dst = ei[N_EDGE + e];
    int pos = atomicAdd(&fillc[dst], 1);
    packed[pos] = ei[e] | (et[e] << 16);
}

// ---- agg: segment mean, one node/wave; 8/4/2/1 MLP ladder
__global__ __launch_bounds__(256) void k_agg(
    const int* __restrict__ rowptr, const int* __restrict__ packed,
    ushort* __restrict__ A, const ushort* __restrict__ relb)
{
    int node = blockIdx.x * 4 + (threadIdx.x >> 6);
    int lane = threadIdx.x & 63;
    int e0 = rowptr[node], e1 = rowptr[node + 1];
    float ax = 0.f, ay = 0.f;
    int e = e0;
    for (; e + 8 <= e1; e += 8) {
        int p0 = packed[e],     p1 = packed[e + 1], p2 = packed[e + 2], p3 = packed[e + 3];
        int p4 = packed[e + 4], p5 = packed[e + 5], p6 = packed[e + 6], p7 = packed[e + 7];
        uint xv0 = *(const uint*)(A + (p0 & 0xFFFF) * 256 + FEAT + lane * 2);
        uint rv0 = *(const uint*)(relb + (p0 >> 16) * FEAT + lane * 2);
        uint xv1 = *(const uint*)(A + (p1 & 0xFFFF) * 256 + FEAT + lane * 2);
        uint rv1 = *(const uint*)(relb + (p1 >> 16) * FEAT + lane * 2);
        uint xv2 = *(const uint*)(A + (p2 & 0xFFFF) * 256 + FEAT + lane * 2);
        uint rv2 = *(const uint*)(relb + (p2 >> 16) * FEAT + lane * 2);
        uint xv3 = *(const uint*)(A + (p3 & 0xFFFF) * 256 + FEAT + lane * 2);
        uint rv3 = *(const uint*)(relb + (p3 >> 16) * FEAT + lane * 2);
        uint xv4 = *(const uint*)(A + (p4 & 0xFFFF) * 256 + FEAT + lane * 2);
        uint rv4 = *(const uint*)(relb + (p4 >> 16) * FEAT + lane * 2);
        uint xv5 = *(const uint*)(A + (p5 & 0xFFFF) * 256 + FEAT + lane * 2);
        uint rv5 = *(const uint*)(relb + (p5 >> 16) * FEAT + lane * 2);
        uint xv6 = *(const uint*)(A + (p6 & 0xFFFF) * 256 + FEAT + lane * 2);
        uint rv6 = *(const uint*)(relb + (p6 >> 16) * FEAT + lane * 2);
        uint xv7 = *(const uint*)(A + (p7 & 0xFFFF) * 256 + FEAT + lane * 2);
        uint rv7 = *(const uint*)(relb + (p7 >> 16) * FEAT + lane * 2);
        ax += bflo(xv0) + bflo(rv0) + bflo(xv1) + bflo(rv1)
            + bflo(xv2) + bflo(rv2) + bflo(xv3) + bflo(rv3)
            + bflo(xv4) + bflo(rv4) + bflo(xv5) + bflo(rv5)
            + bflo(xv6) + bflo(rv6) + bflo(xv7) + bflo(rv7);
        ay += bfhi(xv0) + bfhi(rv0) + bfhi(xv1) + bfhi(rv1)
            + bfhi(xv2) + bfhi(rv2) + bfhi(xv3) + bfhi(rv3)
            + bfhi(xv4) + bfhi(rv4) + bfhi(xv5) + bfhi(rv5)
            + bfhi(xv6) + bfhi(rv6) + bfhi(xv7) + bfhi(rv7);
    }
    for (; e + 4 <= e1; e += 4) {
        int p0 = packed[e], p1 = packed[e + 1], p2 = packed[e + 2], p3 = packed[e + 3];
        uint xv0 = *(const uint*)(A + (p0 & 0xFFFF) * 256 + FEAT + lane * 2);
        uint rv0 = *(const uint*)(relb + (p0 >> 16) * FEAT + lane * 2);
        uint xv1 = *(const uint*)(A + (p1 & 0xFFFF) * 256 + FEAT + lane * 2);
        uint rv1 = *(const uint*)(relb + (p1 >> 16) * FEAT + lane * 2);
        uint xv2 = *(const uint*)(A + (p2 & 0xFFFF) * 256 + FEAT + lane * 2);
        uint rv2 = *(const uint*)(relb + (p2 >> 16) * FEAT + lane * 2);
        uint xv3 = *(const uint*)(A + (p3 & 0xFFFF) * 256 + FEAT + lane * 2);
        uint rv3 = *(const uint*)(relb + (p3 >> 16) * FEAT + lane * 2);
        ax += bflo(xv0) + bflo(rv0) + bflo(xv1) + bflo(rv1)
            + bflo(xv2) + bflo(rv2) + bflo(xv3) + bflo(rv3);
        ay += bfhi(xv0) + bfhi(rv0) + bfhi(xv1) + bfhi(rv1)
            + bfhi(xv2) + bfhi(rv2) + bfhi(xv3) + bfhi(rv3);
    }
    for (; e + 2 <= e1; e += 2) {
        int p0 = packed[e], p1 = packed[e + 1];
        uint xv0 = *(const uint*)(A + (p0 & 0xFFFF) * 256 + FEAT + lane * 2);
        uint rv0 = *(const uint*)(relb + (p0 >> 16) * FEAT + lane * 2);
        uint xv1 = *(const uint*)(A + (p1 & 0xFFFF) * 256 + FEAT + lane * 2);
        uint rv1 = *(const uint*)(relb + (p1 >> 16) * FEAT + lane * 2);
        ax += bflo(xv0) + bflo(rv0) + bflo(xv1) + bflo(rv1);
        ay += bfhi(xv0) + bfhi(rv0) + bfhi(xv1) + bfhi(rv1);
    }
    if (e < e1) {
        int p = packed[e];
        uint xv = *(const uint*)(A + (p & 0xFFFF) * 256 + FEAT + lane * 2);
        uint rv = *(const uint*)(relb + (p >> 16) * FEAT + lane * 2);
        ax += bflo(xv) + bflo(rv);
        ay += bfhi(xv) + bfhi(rv);
    }
    float invd = 1.0f / fmaxf((float)(e1 - e0), 1.0f);
    uint o = (uint)f2bf(ax * invd) | ((uint)f2bf(ay * invd) << 16);
    *(uint*)(A + node * 256 + lane * 2) = o;
}

// ---- hy: fused h = A@W + bm ; y = h@W1 + b1 ; partials -> pb.
// B-loads now fragment-major packed: each load = one contiguous 1KB wave transaction.
__global__ __launch_bounds__(256) void k_hy(
    const ushort* __restrict__ A, const ushort* __restrict__ Wt1,
    const ushort* __restrict__ W1t,
    const float* __restrict__ bm, const float* __restrict__ b1,
    ushort* __restrict__ y, float* __restrict__ pb)
{
    __shared__ ushort a_s[64 * 256];      // 32 KB; swizzled 16B granules
    int tid = threadIdx.x;
    int w = tid >> 6, l = tid & 63;
    int lr = l & 15, lk = l >> 4;
    int m0 = blockIdx.x * 64;

    // stage A-tile: LDS linear, global source swizzled
    {
        const ushort* srcb = A + (size_t)m0 * 256;
        #pragma unroll
        for (int j = 0; j < 8; ++j) {
            int slot = (w * 8 + j) * 64 + l;
            int lrow = slot >> 5, lgr = slot & 31;
            GLL(srcb + lrow * 256 + ((lgr ^ (lrow & 7)) << 3), &a_s[(w * 8 + j) * 512]);
        }
    }
    __syncthreads();

    // ---- phase 1: h = [agg|x] @ [Wm;Wsf] (+bm)
    f32x4 acc[4][4] = {};
    const ushort* Bp = Wt1 + w * 16384 + l * 8;
    #pragma unroll
    for (int kk = 0; kk < 8; ++kk) {
        bf16x8 a[4], b[4];
        #pragma unroll
        for (int mb = 0; mb < 4; ++mb) {
            int row = mb * 16 + lr;
            a[mb] = *(const bf16x8*)&a_s[row * 256 + (((kk * 4 + lk) ^ (lr & 7)) << 3)];
        }
        #pragma unroll
        for (int nb = 0; nb < 4; ++nb) b[nb] = *(const bf16x8*)(Bp + kk * 2048 + nb * 512);
        #pragma unroll
        for (int mb = 0; mb < 4; ++mb)
            #pragma unroll
            for (int nb = 0; nb < 4; ++nb)
                acc[mb][nb] = MFMA(a[mb], b[nb], acc[mb][nb]);
    }
    __syncthreads();   // a_s reads done; reuse for h

    #pragma unroll
    for (int nb = 0; nb < 4; ++nb) {
        int col = w * 64 + nb * 16 + lr;
        float bias = bm[col];
        #pragma unroll
        for (int mb = 0; mb < 4; ++mb)
            #pragma unroll
            for (int r = 0; r < 4; ++r) {
                int row = mb * 16 + lk * 4 + r;
                a_s[row * 256 + (col ^ ((row & 7) << 3))] = f2bf(acc[mb][nb][r] + bias);
            }
    }
    __syncthreads();

    // ---- phase 2: y = h @ W1 (+b1)
    f32x4 acc2[4][4] = {};
    const ushort* B2p = W1t + w * 16384 + l * 8;
    #pragma unroll
    for (int kk = 0; kk < 8; ++kk) {
        bf16x8 a[4], b[4];
        #pragma unroll
        for (int mb = 0; mb < 4; ++mb) {
            int row = mb * 16 + lr;
            a[mb] = *(const bf16x8*)&a_s[row * 256 + ((kk * 32 + lk * 8) ^ ((row & 7) << 3))];
        }
        #pragma unroll
        for (int nb = 0; nb < 4; ++nb) b[nb] = *(const bf16x8*)(B2p + kk * 2048 + nb * 512);
        #pragma unroll
        for (int mb = 0; mb < 4; ++mb)
            #pragma unroll
            for (int nb = 0; nb < 4; ++nb)
                acc2[mb][nb] = MFMA(a[mb], b[nb], acc2[mb][nb]);
    }
    __syncthreads();   // h reads done; reuse a_s for y staging

    #pragma unroll
    for (int nb = 0; nb < 4; ++nb) {
        int col = w * 64 + nb * 16 + lr;
        float b1v = b1[col];
        float cs = 0.f, cq = 0.f;
        #pragma unroll
        for (int mb = 0; mb < 4; ++mb)
            #pragma unroll
            for (int r = 0; r < 4; ++r) {
                int row = mb * 16 + lk * 4 + r;
                float v = acc2[mb][nb][r] + b1v;
                if (m0 + row < N_ENT) { cs += v; cq += v * v; }
                a_s[row * 256 + (col ^ ((row & 7) << 3))] = f2bf(v);
            }
        cs += __shfl_xor(cs, 16); cs += __shfl_xor(cs, 32);
        cq += __shfl_xor(cq, 16); cq += __shfl_xor(cq, 32);
        if (lk == 0) {
            *(float2*)(pb + (size_t)blockIdx.x * 512 + col * 2) = make_float2(cs, cq);
        }
    }
    __syncthreads();
    ushort* yp = y + (size_t)m0 * 256;
    #pragma unroll
    for (int i = 0; i < 8; ++i) {
        int off = i * 2048 + tid * 8;
        *(uint4*)(yp + off) = *(const uint4*)&a_s[off];
    }
}

// ---- red1: parallel stage-1 reduce: 196 blocks x 4 tiles -> pb2[196][512]
__global__ __launch_bounds__(256) void k_red1(
    const float* __restrict__ pb, float* __restrict__ pb2)
{
    int b = blockIdx.x, tid = threadIdx.x;
    int t0 = b * 4;
    float sx = 0.f, sy = 0.f;
    #pragma unroll
    for (int i = 0; i < 4; ++i) {
        int t = t0 + i;
        if (t < NT) {
            float2 v = *(const float2*)(pb + (size_t)t * 512 + tid * 2);
            sx += v.x; sy += v.y;
        }
    }
    *(float2*)(pb2 + (size_t)b * 512 + tid * 2) = make_float2(sx, sy);
}

// ---- red2: stage-2 reduce + BN finalize
__global__ __launch_bounds__(256) void k_red2(
    const float* __restrict__ pb2,
    const float* __restrict__ gamma, const float* __restrict__ beta,
    float* __restrict__ scale, float* __restrict__ shift)
{
    int c = threadIdx.x;
    float s = 0.f, q = 0.f;
    int b = 0;
    #pragma unroll
    for (; b + 8 <= RED_BLKS; b += 8) {
        float2 v0 = *(const float2*)(pb2 + (size_t)(b + 0) * 512 + c * 2);
        float2 v1 = *(const float2*)(pb2 + (size_t)(b + 1) * 512 + c * 2);
        float2 v2 = *(const float2*)(pb2 + (size_t)(b + 2) * 512 + c * 2);
        float2 v3 = *(const float2*)(pb2 + (size_t)(b + 3) * 512 + c * 2);
        float2 v4 = *(const float2*)(pb2 + (size_t)(b + 4) * 512 + c * 2);
        float2 v5 = *(const float2*)(pb2 + (size_t)(b + 5) * 512 + c * 2);
        float2 v6 = *(const float2*)(pb2 + (size_t)(b + 6) * 512 + c * 2);
        float2 v7 = *(const float2*)(pb2 + (size_t)(b + 7) * 512 + c * 2);
        s += v0.x + v1.x + v2.x + v3.x + v4.x + v5.x + v6.x + v7.x;
        q += v0.y + v1.y + v2.y + v3.y + v4.y + v5.y + v6.y + v7.y;
    }
    for (; b < RED_BLKS; ++b) {
        float2 v = *(const float2*)(pb2 + (size_t)b * 512 + c * 2);
        s += v.x; q += v.y;
    }
    const float invn = 1.0f / (float)N_ENT;
    float mean = s * invn;
    float var  = q * invn - mean * mean;
    float rstd = rsqrtf(var + BN_EPS);
    float sc   = gamma[c] * rstd;
    scale[c] = sc;
    shift[c] = beta[c] - mean * sc;
}

// ---- zout: out = relu(y*scale+shift) @ W2 + b2 (fragment-major B).
__global__ __launch_bounds__(256) void k_zout(
    const ushort* __restrict__ y, const float* __restrict__ scale,
    const float* __restrict__ shift, const ushort* __restrict__ W2t,
    const float* __restrict__ b2, float* __restrict__ out)
{
    __shared__ ushort z_s[64 * 256];
    int tid = threadIdx.x;
    int w = tid >> 6, l = tid & 63;
    int lr = l & 15, lk = l >> 4;
    int m0 = blockIdx.x * 64;

    {
        const ushort* srcb = y + (size_t)m0 * 256;
        #pragma unroll
        for (int j = 0; j < 8; ++j)
            GLL(srcb + ((w * 8 + j) * 64 + l) * 8, &z_s[(w * 8 + j) * 512]);
    }
    __syncthreads();

    f32x4 acc[4][2] = {};
    const ushort* Bp = W2t + w * 8192 + l * 8;
    #pragma unroll
    for (int kk = 0; kk < 8; ++kk) {
        int kb = kk * 32 + lk * 8;
        float scv[8], shv[8];
        *(float4*)&scv[0] = *(const float4*)(scale + kb);
        *(float4*)&scv[4] = *(const float4*)(scale + kb + 4);
        *(float4*)&shv[0] = *(const float4*)(shift + kb);
        *(float4*)&shv[4] = *(const float4*)(shift + kb + 4);
        bf16x8 b[2];
        #pragma unroll
        for (int nb = 0; nb < 2; ++nb) b[nb] = *(const bf16x8*)(Bp + kk * 1024 + nb * 512);
        bf16x8 a[4];
        #pragma unroll
        for (int mb = 0; mb < 4; ++mb) {
            int row = mb * 16 + lr;
            uint4 uv = *(const uint4*)&z_s[row * 256 + (kb ^ ((row & 7) << 3))];
            uint wd[4] = {uv.x, uv.y, uv.z, uv.w};
            #pragma unroll
            for (int j = 0; j < 8; ++j) {
                uint bits = (j & 1) ? (wd[j >> 1] & 0xFFFF0000u) : (wd[j >> 1] << 16);
                float f = __uint_as_float(bits);
                float z = fmaxf(f * scv[j] + shv[j], 0.f);
                a[mb][j] = (short)f2bf(z);
            }
        }
        #pragma unroll
        for (int mb = 0; mb < 4; ++mb)
            #pragma unroll
            for (int nb = 0; nb < 2; ++nb)
                acc[mb][nb] = MFMA(a[mb], b[nb], acc[mb][nb]);
    }
    #pragma unroll
    for (int nb = 0; nb < 2; ++nb) {
        int col = w * 32 + nb * 16 + lr;
        float b2v = b2[col];
        #pragma unroll
        for (int mb = 0; mb < 4; ++mb)
            #pragma unroll
            for (int r = 0; r < 4; ++r) {
                int row = m0 + mb * 16 + lk * 4 + r;
                if (row < N_ENT) out[row * OUT_D + col] = acc[mb][nb][r] + b2v;
            }
    }
}

extern "C" void kernel_launch(void* const* d_in, const int* in_sizes, int n_in,
                              void* d_out, int out_size, void* d_ws, size_t ws_size,
                              hipStream_t stream)
{
    const int*   ei    = (const int*)d_in[0];
    const int*   et    = (const int*)d_in[1];
    const float* x     = (const float*)d_in[2];
    const float* rel   = (const float*)d_in[3];
    const float* Wm    = (const float*)d_in[4];
    const float* bm    = (const float*)d_in[5];
    const float* Wsf   = (const float*)d_in[6];
    const float* W1    = (const float*)d_in[7];
    const float* b1    = (const float*)d_in[8];
    const float* gamma = (const float*)d_in[9];
    const float* beta  = (const float*)d_in[10];
    const float* W2    = (const float*)d_in[11];
    const float* b2    = (const float*)d_in[12];
    float* out = (float*)d_out;

    char* ws = (char*)d_ws;
    int*    degi   = (int*)(ws + OFF_DEGI);
    float*  scale  = (float*)(ws + OFF_SCALE);
    float*  shift  = (float*)(ws + OFF_SHIFT);
    ushort* relb   = (ushort*)(ws + OFF_RELB);
    ushort* Wt1    = (ushort*)(ws + OFF_WT1);
    ushort* W1t    = (ushort*)(ws + OFF_W1T);
    ushort* W2t    = (ushort*)(ws + OFF_W2T);
    ushort* A      = (ushort*)(ws + OFF_A);
    ushort* y      = (ushort*)(ws + OFF_Y);
    int*    rowptr = (int*)(ws + OFF_ROWPTR);
    int*    fillc  = (int*)(ws + OFF_FILLC);
    int*    packed = (int*)(ws + OFF_PACKED);
    int*    bsum   = (int*)(ws + OFF_BSUM);
    int*    boff   = (int*)(ws + OFF_BOFF);
    float*  pb     = (float*)(ws + OFF_PB);
    float*  pb2    = (float*)(ws + OFF_PB2);

    hipMemsetAsync(ws + OFF_DEGI, 0, 200000, stream);
    hipMemsetAsync(ws + OFF_A + N_ENT * 512, 0, (MROWS - N_ENT) * 512, stream);

    k_prep <<<6160, 256, 0, stream>>>(x, ei, Wm, Wsf, W1, W2, rel, A, degi, Wt1, W1t, W2t, relb);
    k_bsum <<<SCAN_BLKS, 256, 0, stream>>>(degi, bsum);
    k_boff <<<1, 256, 0, stream>>>(bsum, boff, rowptr);
    k_scan2<<<SCAN_BLKS, 256, 0, stream>>>(degi, boff, rowptr, fillc);
    k_fill <<<(N_EDGE + 255) / 256, 256, 0, stream>>>(ei, et, fillc, packed);
    k_agg  <<<N_ENT / 4, 256, 0, stream>>>(rowptr, packed, A, relb);
    k_hy   <<<NT, 256, 0, stream>>>(A, Wt1, W1t, bm, b1, y, pb);
    k_red1 <<<RED_BLKS, 256, 0, stream>>>(pb, pb2);
    k_red2 <<<1, 256, 0, stream>>>(pb2, gamma, beta, scale, shift);
    k_zout <<<NT, 256, 0, stream>>>(y, scale, shift, W2t, b2, out);
}